// Round 2
// baseline (3530.392 us; speedup 1.0000x reference)
//
#include <hip/hip_runtime.h>
#include <cstdint>
#include <cstddef>

#define NN 50000
#define EE 800000
#define GG 8

typedef unsigned int u32;

// order-preserving float->uint encode for atomicMax
__device__ __forceinline__ u32 encf(float f){
  u32 b = __float_as_uint(f);
  return (b & 0x80000000u) ? ~b : (b | 0x80000000u);
}
__device__ __forceinline__ float decf(u32 u){
  u32 b = (u & 0x80000000u) ? (u ^ 0x80000000u) : ~u;
  return __uint_as_float(b);
}

// ---------------- CSR build ----------------
__global__ void k_count(const int* __restrict__ ei, int* __restrict__ cnt){
  int e = blockIdx.x*256 + threadIdx.x;
  if (e < EE) atomicAdd(&cnt[ei[EE + e]], 1);
}

__global__ __launch_bounds__(1024) void k_scan(const int* __restrict__ CNT, int* __restrict__ OFF, int* __restrict__ CUR){
  __shared__ int buf[1024];
  __shared__ int carry_s;
  int tid = threadIdx.x;
  if (tid==0) carry_s = 0;
  __syncthreads();
  for (int base=0; base<NN; base+=1024){
    int v = (base+tid<NN) ? CNT[base+tid] : 0;
    buf[tid] = v; __syncthreads();
    for (int o=1;o<1024;o<<=1){
      int x = (tid>=o) ? buf[tid-o] : 0;
      __syncthreads();
      buf[tid] += x;
      __syncthreads();
    }
    int carry = carry_s;
    int excl = carry + buf[tid] - v;
    if (base+tid<NN){ OFF[base+tid]=excl; CUR[base+tid]=excl; }
    int tot = buf[1023];
    __syncthreads();
    if (tid==0) carry_s = carry + tot;
    __syncthreads();
  }
  if (tid==0) OFF[NN] = carry_s;
}

__global__ void k_scatter(const int* __restrict__ ei, int* __restrict__ cur, int* __restrict__ csr){
  int e = blockIdx.x*256 + threadIdx.x;
  if (e < EE){
    int d = ei[EE+e];
    int p = atomicAdd(&cur[d], 1);
    csr[p] = e;
  }
}

// ---------------- generic linear: Y = act(X @ W + b) ----------------
template<int CI, int CO, int ACT>
__global__ __launch_bounds__(256) void k_lin(const float* __restrict__ X, const float* __restrict__ W,
                                             const float* __restrict__ Bb, float* __restrict__ Y, int R){
  const int RPB = 16, SLOTS = 256/CO, J = RPB/SLOTS, NKC = CI/64;
  __shared__ float wl[64*CO];
  __shared__ float xs[RPB][65];
  int tid = threadIdx.x;
  int c = tid % CO, slot = tid / CO;
  int r0 = blockIdx.x * RPB;
  float acc[J];
#pragma unroll
  for (int j=0;j<J;++j) acc[j]=0.f;
  for (int kc=0; kc<NKC; ++kc){
    const float4* ws4 = (const float4*)(W + (size_t)kc*64*CO);
    float4* wl4 = (float4*)wl;
    for (int i=tid; i<64*CO/4; i+=256) wl4[i] = ws4[i];
    for (int i=tid; i<RPB*64; i+=256){
      int r = i>>6, k = i&63;
      float v = 0.f;
      if (r0 + r < R) v = X[(size_t)(r0+r)*CI + kc*64 + k];
      xs[r][k] = v;
    }
    __syncthreads();
#pragma unroll 4
    for (int k=0;k<64;++k){
      float w = wl[k*CO + c];
#pragma unroll
      for (int j=0;j<J;++j) acc[j] += xs[slot + j*SLOTS][k] * w;
    }
    __syncthreads();
  }
  float b = Bb ? Bb[c] : 0.f;
#pragma unroll
  for (int j=0;j<J;++j){
    int r = r0 + slot + j*SLOTS;
    if (r < R){
      float v = acc[j] + b;
      if (ACT==1) v = fmaxf(v, 0.f);
      Y[(size_t)r*CO + c] = v;
    }
  }
}

// ---------------- edge encoder: relu(ea@W1+b1)@W2+b2, 16 edges/block ----------------
__global__ __launch_bounds__(256) void k_edge_enc(const float* __restrict__ EA,
    const float* __restrict__ W1, const float* __restrict__ B1,
    const float* __restrict__ W2, const float* __restrict__ B2, float* __restrict__ OUT){
  __shared__ float w1l[64*64];
  __shared__ float w2l[64*64];
  __shared__ float xs[16][65];
  __shared__ float ms[16][65];
  int tid = threadIdx.x, c = tid & 63, slot = tid >> 6;
  for (int i=tid; i<64*64/4; i+=256){
    ((float4*)w1l)[i] = ((const float4*)W1)[i];
    ((float4*)w2l)[i] = ((const float4*)W2)[i];
  }
  size_t base = (size_t)blockIdx.x * 16 * 64;
  for (int i=tid; i<16*64; i+=256) xs[i>>6][i&63] = EA[base + i];
  __syncthreads();
  float acc[4];
#pragma unroll
  for (int j=0;j<4;++j) acc[j]=0.f;
#pragma unroll 4
  for (int k=0;k<64;++k){
    float w = w1l[k*64 + c];
#pragma unroll
    for (int j=0;j<4;++j) acc[j] += xs[j*4+slot][k] * w;
  }
  float b1 = B1[c];
#pragma unroll
  for (int j=0;j<4;++j) ms[j*4+slot][c] = fmaxf(acc[j] + b1, 0.f);
  __syncthreads();
#pragma unroll
  for (int j=0;j<4;++j) acc[j]=0.f;
#pragma unroll 4
  for (int k=0;k<64;++k){
    float w = w2l[k*64 + c];
#pragma unroll
    for (int j=0;j<4;++j) acc[j] += ms[j*4+slot][k] * w;
  }
  float b2 = B2[c];
#pragma unroll
  for (int j=0;j<4;++j) OUT[base + (size_t)(j*4+slot)*64 + c] = acc[j] + b2;
}

// ---------------- GATv2 aggregation, layer 1 (H=4,D=32,HD=128) ----------------
// 4 waves/block, one dst node per wave; thread t owns channels 2t,2t+1; head = t/16
__global__ __launch_bounds__(256) void k_aggr1(const float* __restrict__ XL, const float* __restrict__ XR,
    const float* __restrict__ EA, const float* __restrict__ WE, const float* __restrict__ ATT,
    const float* __restrict__ BIAS, const int* __restrict__ SRC, const int* __restrict__ OFF,
    const int* __restrict__ CSR, float* __restrict__ OUT){
  __shared__ float wel[64*128];
  int tid = threadIdx.x, t = tid & 63, wid = tid >> 6;
  for (int i=tid; i<64*128/4; i+=256) ((float4*)wel)[i] = ((const float4*)WE)[i];
  __syncthreads();
  int n = blockIdx.x*4 + wid;
  float att0 = ATT[2*t], att1 = ATT[2*t+1];
  float2 xrv = *(const float2*)(XR + (size_t)n*128 + 2*t);
  int beg = OFF[n], end = OFF[n+1];
  float m = -INFINITY, l = 0.f, a0 = 0.f, a1 = 0.f;
  const float2* wel2 = (const float2*)wel;
  for (int i=beg; i<end; ++i){
    int e = CSR[i];
    int s = SRC[e];
    float eat = EA[(size_t)e*64 + t];
    float2 xlv = *(const float2*)(XL + (size_t)s*128 + 2*t);
    float ee0=0.f, ee1=0.f;
#pragma unroll 8
    for (int k=0;k<64;++k){
      float a = __shfl(eat, k);
      float2 wv = wel2[(size_t)k*64 + t];
      ee0 += a * wv.x;
      ee1 += a * wv.y;
    }
    float s0 = xrv.x + xlv.x + ee0; s0 = s0>0.f ? s0 : 0.2f*s0;
    float s1 = xrv.y + xlv.y + ee1; s1 = s1>0.f ? s1 : 0.2f*s1;
    float pa = s0*att0 + s1*att1;
    pa += __shfl_xor(pa,1); pa += __shfl_xor(pa,2); pa += __shfl_xor(pa,4); pa += __shfl_xor(pa,8);
    if (pa > m){
      float sc = __expf(m - pa);     // m==-inf -> 0
      a0 = a0*sc + xlv.x; a1 = a1*sc + xlv.y; l = l*sc + 1.f; m = pa;
    } else {
      float p = __expf(pa - m);
      a0 += p*xlv.x; a1 += p*xlv.y; l += p;
    }
  }
  float inv = 1.f/(l + 1e-16f);
  *(float2*)(OUT + (size_t)n*128 + 2*t) = make_float2(a0*inv + BIAS[2*t], a1*inv + BIAS[2*t+1]);
}

// ---------------- GATv2 aggregation, layer 2 (H=2,D=32,HD=64) ----------------
__global__ __launch_bounds__(256) void k_aggr2(const float* __restrict__ XL, const float* __restrict__ XR,
    const float* __restrict__ EA, const float* __restrict__ WE, const float* __restrict__ ATT,
    const float* __restrict__ BIAS, const int* __restrict__ SRC, const int* __restrict__ OFF,
    const int* __restrict__ CSR, float* __restrict__ OUT){
  __shared__ float wel[64*64];
  int tid = threadIdx.x, t = tid & 63, wid = tid >> 6;
  for (int i=tid; i<64*64/4; i+=256) ((float4*)wel)[i] = ((const float4*)WE)[i];
  __syncthreads();
  int n = blockIdx.x*4 + wid;
  float attc = ATT[t];
  float xrv = XR[(size_t)n*64 + t];
  int beg = OFF[n], end = OFF[n+1];
  float m = -INFINITY, l = 0.f, a0 = 0.f;
  for (int i=beg; i<end; ++i){
    int e = CSR[i];
    int s = SRC[e];
    float eat = EA[(size_t)e*64 + t];
    float xlv = XL[(size_t)s*64 + t];
    float ee = 0.f;
#pragma unroll 8
    for (int k=0;k<64;++k) ee += __shfl(eat, k) * wel[k*64 + t];
    float s0 = xrv + xlv + ee; s0 = s0>0.f ? s0 : 0.2f*s0;
    float pa = s0*attc;
    pa += __shfl_xor(pa,1); pa += __shfl_xor(pa,2); pa += __shfl_xor(pa,4);
    pa += __shfl_xor(pa,8); pa += __shfl_xor(pa,16);
    if (pa > m){
      float sc = __expf(m - pa);
      a0 = a0*sc + xlv; l = l*sc + 1.f; m = pa;
    } else {
      float p = __expf(pa - m);
      a0 += p*xlv; l += p;
    }
  }
  float inv = 1.f/(l + 1e-16f);
  OUT[(size_t)n*64 + t] = a0*inv + BIAS[t];
}

// ---------------- LN(128) + ELU, in-place ----------------
__global__ __launch_bounds__(256) void k_ln_elu(float* __restrict__ H, const float* __restrict__ G_,
                                                const float* __restrict__ B_, int R){
  int lane = threadIdx.x & 63, w = threadIdx.x >> 6;
  int n = blockIdx.x*4 + w;
  if (n >= R) return;
  float2 v = *(float2*)(H + (size_t)n*128 + 2*lane);
  float s = v.x + v.y;
  float q = v.x*v.x + v.y*v.y;
#pragma unroll
  for (int o=1;o<64;o<<=1){ s += __shfl_xor(s,o); q += __shfl_xor(q,o); }
  float mean = s * (1.f/128.f);
  float var  = q * (1.f/128.f) - mean*mean;
  float r = rsqrtf(var + 1e-5f);
  float y0 = (v.x-mean)*r*G_[2*lane]   + B_[2*lane];
  float y1 = (v.y-mean)*r*G_[2*lane+1] + B_[2*lane+1];
  y0 = y0>0.f ? y0 : __expf(y0)-1.f;
  y1 = y1>0.f ? y1 : __expf(y1)-1.f;
  *(float2*)(H + (size_t)n*128 + 2*lane) = make_float2(y0,y1);
}

// ---------------- LN(64) + residual GEMV + ELU -> node_emb (f32 out) ----------------
__global__ __launch_bounds__(256) void k_res(const float* __restrict__ GO, const float* __restrict__ H0,
    const float* __restrict__ RPW, const float* __restrict__ RPB_, const float* __restrict__ G_,
    const float* __restrict__ B_, float* __restrict__ NE, int R){
  __shared__ float rl[64*64];
  int tid = threadIdx.x, lane = tid & 63, wv = tid >> 6;
  for (int i=tid; i<64*64/4; i+=256) ((float4*)rl)[i] = ((const float4*)RPW)[i];
  __syncthreads();
  int n = blockIdx.x*4 + wv;
  if (n >= R) return;
  float x = GO[(size_t)n*64 + lane];
  float s = x, q = x*x;
#pragma unroll
  for (int o=1;o<64;o<<=1){ s += __shfl_xor(s,o); q += __shfl_xor(q,o); }
  float mean = s * (1.f/64.f);
  float var  = q * (1.f/64.f) - mean*mean;
  float r = rsqrtf(var + 1e-5f);
  float ln = (x-mean)*r*G_[lane] + B_[lane];
  float h0v = H0[(size_t)n*64 + lane];
  float acc = 0.f;
#pragma unroll 8
  for (int k=0;k<64;++k) acc += __shfl(h0v,k) * rl[k*64+lane];
  float y = ln + acc + RPB_[lane];
  y = y>0.f ? y : __expf(y)-1.f;
  NE[(size_t)n*64+lane] = y;
}

// ---------------- gate second layer: dot(mid,w2)+b2 ----------------
__global__ __launch_bounds__(256) void k_gate2(const float* __restrict__ MID, const float* __restrict__ W2,
                                               const float* __restrict__ B2, float* __restrict__ GATE, int R){
  int lane = threadIdx.x & 63, wv = threadIdx.x >> 6;
  int n = blockIdx.x*4 + wv;
  if (n >= R) return;
  float p = MID[(size_t)n*64 + lane] * W2[lane];
#pragma unroll
  for (int o=1;o<64;o<<=1) p += __shfl_xor(p,o);
  if (lane==0) GATE[n] = p + B2[0];
}

// ---------------- pooling ----------------
__global__ void k_pool_max(const float* __restrict__ GATE, const int* __restrict__ BATCH, u32* __restrict__ GMAX){
  int i = blockIdx.x*256 + threadIdx.x;
  if (i < NN) atomicMax(&GMAX[BATCH[i]], encf(GATE[i]));
}

__global__ __launch_bounds__(64) void k_pool_acc(const float* __restrict__ NE, const float* __restrict__ GATE,
    const int* __restrict__ BATCH, const u32* __restrict__ GMAX, float* __restrict__ GACC, float* __restrict__ GDEN){
  int t = threadIdx.x;
  int n0 = blockIdx.x*256;
  int n1 = n0+256; if (n1 > NN) n1 = NN;
  int curg = -1; float acc = 0.f, dl = 0.f, gm = 0.f;
  for (int n=n0; n<n1; ++n){
    int g = BATCH[n];
    if (g != curg){
      if (curg >= 0){ atomicAdd(&GACC[curg*64+t], acc); if (t==0) atomicAdd(&GDEN[curg], dl); }
      curg = g; acc = 0.f; dl = 0.f;
      float d = decf(GMAX[g]);
      gm = isfinite(d) ? d : 0.f;
    }
    float p = __expf(GATE[n] - gm);
    acc += p * NE[(size_t)n*64 + t];
    if (t==0) dl += p;
  }
  if (curg >= 0){ atomicAdd(&GACC[curg*64+t], acc); if (t==0) atomicAdd(&GDEN[curg], dl); }
}

__global__ __launch_bounds__(64) void k_scene(const float* __restrict__ GACC, const float* __restrict__ GDEN,
    const float* __restrict__ W1, const float* __restrict__ B1, const float* __restrict__ W2,
    const float* __restrict__ B2, float* __restrict__ Z){
  __shared__ float gv[GG][64];
  __shared__ float md[GG][64];
  int t = threadIdx.x;
  for (int g=0; g<GG; ++g) gv[g][t] = GACC[g*64+t] / (GDEN[g] + 1e-16f);
  __syncthreads();
  for (int g=0; g<GG; ++g){
    float m = 0.f;
    for (int k=0;k<64;++k) m += gv[g][k]*W1[k*64+t];
    md[g][t] = fmaxf(m + B1[t], 0.f);
  }
  __syncthreads();
  if (t < 32){
    for (int g=0; g<GG; ++g){
      float o = 0.f;
      for (int k=0;k<64;++k) o += md[g][k]*W2[k*32+t];
      Z[g*32+t] = o + B2[t];
    }
  }
}

// ---------------- launch ----------------
extern "C" void kernel_launch(void* const* d_in, const int* in_sizes, int n_in,
                              void* d_out, int out_size, void* d_ws, size_t ws_size,
                              hipStream_t stream){
  const float* x   = (const float*)d_in[0];
  const int* ei    = (const int*)d_in[1];
  const float* ea  = (const float*)d_in[2];
  const int* batch = (const int*)d_in[3];
  const float* ne_w1 = (const float*)d_in[4];  const float* ne_b1 = (const float*)d_in[5];
  const float* ne_w2 = (const float*)d_in[6];  const float* ne_b2 = (const float*)d_in[7];
  const float* ee_w1 = (const float*)d_in[8];  const float* ee_b1 = (const float*)d_in[9];
  const float* ee_w2 = (const float*)d_in[10]; const float* ee_b2 = (const float*)d_in[11];
  const float* g1_wl = (const float*)d_in[12]; const float* g1_bl = (const float*)d_in[13];
  const float* g1_wr = (const float*)d_in[14]; const float* g1_br = (const float*)d_in[15];
  const float* g1_we = (const float*)d_in[16];
  const float* g1_att= (const float*)d_in[17]; const float* g1_b  = (const float*)d_in[18];
  const float* n1_g  = (const float*)d_in[19]; const float* n1_b  = (const float*)d_in[20];
  const float* g2_wl = (const float*)d_in[21]; const float* g2_bl = (const float*)d_in[22];
  const float* g2_wr = (const float*)d_in[23]; const float* g2_br = (const float*)d_in[24];
  const float* g2_we = (const float*)d_in[25];
  const float* g2_att= (const float*)d_in[26]; const float* g2_b  = (const float*)d_in[27];
  const float* n2_g  = (const float*)d_in[28]; const float* n2_b  = (const float*)d_in[29];
  const float* rp_w  = (const float*)d_in[30]; const float* rp_b  = (const float*)d_in[31];
  const float* gt_w1 = (const float*)d_in[32]; const float* gt_b1 = (const float*)d_in[33];
  const float* gt_w2 = (const float*)d_in[34]; const float* gt_b2 = (const float*)d_in[35];
  const float* se_w1 = (const float*)d_in[36]; const float* se_b1 = (const float*)d_in[37];
  const float* se_w2 = (const float*)d_in[38]; const float* se_b2 = (const float*)d_in[39];

  char* ws = (char*)d_ws;
  size_t o = 0;
  auto alloc = [&](size_t bytes){ size_t r = o; o += (bytes + 255) & ~(size_t)255; return r; };
  float* h0   = (float*)(ws + alloc((size_t)NN*64*4));
  float* ta   = (float*)(ws + alloc((size_t)NN*128*4));   // mid / xl1 / xl2 / gate_mid
  float* tb   = (float*)(ws + alloc((size_t)NN*128*4));   // xr1 / xr2
  float* tc   = (float*)(ws + alloc((size_t)NN*128*4));   // gat1 out -> h1 -> gat2 out
  float* gate = (float*)(ws + alloc((size_t)NN*4));
  int*   cnt  = (int*)  (ws + alloc((size_t)NN*4));       // counts, then scatter cursor
  int*   off  = (int*)  (ws + alloc((size_t)(NN+1)*4));
  int*   csr  = (int*)  (ws + alloc((size_t)EE*4));
  char*  poolb= ws + alloc(4096);
  u32*   gmax = (u32*)poolb;            // 8
  float* gden = (float*)(poolb + 64);   // 8
  float* gacc = (float*)(poolb + 128);  // 8*64
  if (o > ws_size) return;

  float* out_z  = (float*)d_out;
  float* out_ne = out_z + 256;
  float* out_er = out_ne + (size_t)NN*64;

  // CSR by dst
  hipMemsetAsync(cnt, 0, (size_t)NN*4, stream);
  hipMemsetAsync(poolb, 0, 4096, stream);
  k_count<<<(EE+255)/256, 256, 0, stream>>>(ei, cnt);
  k_scan<<<1, 1024, 0, stream>>>(cnt, off, cnt);
  k_scatter<<<(EE+255)/256, 256, 0, stream>>>(ei, cnt, csr);

  // node encoder: x -> mid(ta) -> h0
  k_lin<256,128,1><<<(NN+15)/16, 256, 0, stream>>>(x,  ne_w1, ne_b1, ta, NN);
  k_lin<128,64, 0><<<(NN+15)/16, 256, 0, stream>>>(ta, ne_w2, ne_b2, h0, NN);

  // GAT layer 1
  k_lin<64,128,0><<<(NN+15)/16, 256, 0, stream>>>(h0, g1_wl, g1_bl, ta, NN);
  k_lin<64,128,0><<<(NN+15)/16, 256, 0, stream>>>(h0, g1_wr, g1_br, tb, NN);
  k_aggr1<<<NN/4, 256, 0, stream>>>(ta, tb, ea, g1_we, g1_att, g1_b, ei, off, csr, tc);
  k_ln_elu<<<(NN+3)/4, 256, 0, stream>>>(tc, n1_g, n1_b, NN);

  // GAT layer 2
  k_lin<128,64,0><<<(NN+15)/16, 256, 0, stream>>>(tc, g2_wl, g2_bl, ta, NN);
  k_lin<128,64,0><<<(NN+15)/16, 256, 0, stream>>>(tc, g2_wr, g2_br, tb, NN);
  k_aggr2<<<NN/4, 256, 0, stream>>>(ta, tb, ea, g2_we, g2_att, g2_b, ei, off, csr, tc);
  k_res<<<(NN+3)/4, 256, 0, stream>>>(tc, h0, rp_w, rp_b, n2_g, n2_b, out_ne, NN);

  // edge representations (direct to d_out)
  k_edge_enc<<<EE/16, 256, 0, stream>>>(ea, ee_w1, ee_b1, ee_w2, ee_b2, out_er);

  // attentional pooling + scene encoder
  k_lin<64,64,1><<<(NN+15)/16, 256, 0, stream>>>(out_ne, gt_w1, gt_b1, ta, NN);
  k_gate2<<<(NN+3)/4, 256, 0, stream>>>(ta, gt_w2, gt_b2, gate, NN);
  k_pool_max<<<(NN+255)/256, 256, 0, stream>>>(gate, batch, gmax);
  k_pool_acc<<<(NN+255)/256, 64, 0, stream>>>(out_ne, gate, batch, gmax, gacc, gden);
  k_scene<<<1, 64, 0, stream>>>(gacc, gden, se_w1, se_b1, se_w2, se_b2, out_z);
}

// Round 3
// 2525.657 us; speedup vs baseline: 1.3978x; 1.3978x over previous
//
#include <hip/hip_runtime.h>
#include <cstdint>
#include <cstddef>

#define NN 50000
#define EE 800000
#define GG 8

typedef unsigned int u32;

__device__ __forceinline__ u32 encf(float f){
  u32 b = __float_as_uint(f);
  return (b & 0x80000000u) ? ~b : (b | 0x80000000u);
}
__device__ __forceinline__ float decf(u32 u){
  u32 b = (u & 0x80000000u) ? (u ^ 0x80000000u) : ~u;
  return __uint_as_float(b);
}
__device__ __forceinline__ void fma4(float4& a, float s, const float4& w){
  a.x += s*w.x; a.y += s*w.y; a.z += s*w.z; a.w += s*w.w;
}
__device__ __forceinline__ float4 lk4(float4 v){
  v.x = v.x>0.f ? v.x : 0.2f*v.x;
  v.y = v.y>0.f ? v.y : 0.2f*v.y;
  v.z = v.z>0.f ? v.z : 0.2f*v.z;
  v.w = v.w>0.f ? v.w : 0.2f*v.w;
  return v;
}

// ---------------- CSR build ----------------
__global__ void k_count(const int* __restrict__ ei, int* __restrict__ cnt){
  int e = blockIdx.x*256 + threadIdx.x;
  if (e < EE) atomicAdd(&cnt[ei[EE + e]], 1);
}

__global__ __launch_bounds__(1024) void k_scan(const int* __restrict__ CNT, int* __restrict__ OFF, int* __restrict__ CUR){
  __shared__ int buf[1024];
  __shared__ int carry_s;
  int tid = threadIdx.x;
  if (tid==0) carry_s = 0;
  __syncthreads();
  for (int base=0; base<NN; base+=1024){
    int v = (base+tid<NN) ? CNT[base+tid] : 0;
    buf[tid] = v; __syncthreads();
    for (int o=1;o<1024;o<<=1){
      int x = (tid>=o) ? buf[tid-o] : 0;
      __syncthreads();
      buf[tid] += x;
      __syncthreads();
    }
    int carry = carry_s;
    int excl = carry + buf[tid] - v;
    if (base+tid<NN){ OFF[base+tid]=excl; CUR[base+tid]=excl; }
    int tot = buf[1023];
    __syncthreads();
    if (tid==0) carry_s = carry + tot;
    __syncthreads();
  }
  if (tid==0) OFF[NN] = carry_s;
}

__global__ void k_scatter(const int* __restrict__ ei, int* __restrict__ cur, int* __restrict__ csr){
  int e = blockIdx.x*256 + threadIdx.x;
  if (e < EE){
    int d = ei[EE+e];
    int p = atomicAdd(&cur[d], 1);
    csr[p] = e;
  }
}

// ---------------- generic linear: Y = act(X @ W + b), k-vectorized ----------------
template<int CI, int CO, int ACT>
__global__ __launch_bounds__(256) void k_lin(const float* __restrict__ X, const float* __restrict__ W,
                                             const float* __restrict__ Bb, float* __restrict__ Y, int R){
  const int RPB = 16, SLOTS = 256/CO, J = RPB/SLOTS, NKC = CI/64;
  __shared__ float wl[64*CO];
  __shared__ float xs[RPB][68];
  int tid = threadIdx.x;
  int c = tid % CO, slot = tid / CO;
  int r0 = blockIdx.x * RPB;
  float acc[J];
#pragma unroll
  for (int j=0;j<J;++j) acc[j]=0.f;
  for (int kc=0; kc<NKC; ++kc){
    const float4* ws4 = (const float4*)(W + (size_t)kc*64*CO);
    float4* wl4 = (float4*)wl;
    for (int i=tid; i<64*CO/4; i+=256) wl4[i] = ws4[i];
    for (int i=tid; i<RPB*64; i+=256){
      int r = i>>6, k = i&63;
      float v = 0.f;
      if (r0 + r < R) v = X[(size_t)(r0+r)*CI + kc*64 + k];
      xs[r][k] = v;
    }
    __syncthreads();
#pragma unroll
    for (int k4=0;k4<16;++k4){
      float w0 = wl[(4*k4+0)*CO+c], w1 = wl[(4*k4+1)*CO+c];
      float w2 = wl[(4*k4+2)*CO+c], w3 = wl[(4*k4+3)*CO+c];
#pragma unroll
      for (int j=0;j<J;++j){
        float4 xv = *(const float4*)&xs[slot + j*SLOTS][k4*4];
        acc[j] += xv.x*w0 + xv.y*w1 + xv.z*w2 + xv.w*w3;
      }
    }
    __syncthreads();
  }
  float b = Bb ? Bb[c] : 0.f;
#pragma unroll
  for (int j=0;j<J;++j){
    int r = r0 + slot + j*SLOTS;
    if (r < R){
      float v = acc[j] + b;
      if (ACT==1) v = fmaxf(v, 0.f);
      Y[(size_t)r*CO + c] = v;
    }
  }
}

// ---------------- edge encoder: relu(ea@W1+b1)@W2+b2, 16 edges/block ----------------
__global__ __launch_bounds__(256) void k_edge_enc(const float* __restrict__ EA,
    const float* __restrict__ W1, const float* __restrict__ B1,
    const float* __restrict__ W2, const float* __restrict__ B2, float* __restrict__ OUT){
  __shared__ float w1l[64*64];
  __shared__ float w2l[64*64];
  __shared__ float xs[16][68];
  __shared__ float ms[16][68];
  int tid = threadIdx.x, c = tid & 63, slot = tid >> 6;
  for (int i=tid; i<64*64/4; i+=256){
    ((float4*)w1l)[i] = ((const float4*)W1)[i];
    ((float4*)w2l)[i] = ((const float4*)W2)[i];
  }
  size_t base = (size_t)blockIdx.x * 16 * 64;
  {
    const float4* ea4 = (const float4*)(EA + base);
    for (int i=tid; i<16*16; i+=256) *(float4*)&xs[i>>4][(i&15)*4] = ea4[i];
  }
  __syncthreads();
  float acc[4];
#pragma unroll
  for (int j=0;j<4;++j) acc[j]=0.f;
#pragma unroll
  for (int k4=0;k4<16;++k4){
    float w0 = w1l[(4*k4+0)*64+c], w1 = w1l[(4*k4+1)*64+c];
    float w2 = w1l[(4*k4+2)*64+c], w3 = w1l[(4*k4+3)*64+c];
#pragma unroll
    for (int j=0;j<4;++j){
      float4 xv = *(const float4*)&xs[j*4+slot][k4*4];
      acc[j] += xv.x*w0 + xv.y*w1 + xv.z*w2 + xv.w*w3;
    }
  }
  float b1 = B1[c];
#pragma unroll
  for (int j=0;j<4;++j) ms[j*4+slot][c] = fmaxf(acc[j] + b1, 0.f);
  __syncthreads();
#pragma unroll
  for (int j=0;j<4;++j) acc[j]=0.f;
#pragma unroll
  for (int k4=0;k4<16;++k4){
    float w0 = w2l[(4*k4+0)*64+c], w1 = w2l[(4*k4+1)*64+c];
    float w2 = w2l[(4*k4+2)*64+c], w3 = w2l[(4*k4+3)*64+c];
#pragma unroll
    for (int j=0;j<4;++j){
      float4 xv = *(const float4*)&ms[j*4+slot][k4*4];
      acc[j] += xv.x*w0 + xv.y*w1 + xv.z*w2 + xv.w*w3;
    }
  }
  float b2 = B2[c];
#pragma unroll
  for (int j=0;j<4;++j) OUT[base + (size_t)(j*4+slot)*64 + c] = acc[j] + b2;
}

// ---------------- alpha layer 1: edge-parallel logits, H=4, D=32, HD=128 ----------------
// 16 edges/block; thread = (cg in [0,32), slot in [0,8)); 4 cols x 2 rows per thread
__global__ __launch_bounds__(256) void k_alpha1(const float* __restrict__ XL, const float* __restrict__ XR,
    const float* __restrict__ EA, const float* __restrict__ WE, const float* __restrict__ ATT,
    const int* __restrict__ EI, float* __restrict__ ALPHA){
  __shared__ float wel[64*128];
  __shared__ float eas[16][64];
  __shared__ int ssrc[16], sdst[16];
  int tid = threadIdx.x;
  int e0 = blockIdx.x*16;
  for (int i=tid; i<64*128/4; i+=256) ((float4*)wel)[i] = ((const float4*)WE)[i];
  {
    const float4* ea4 = (const float4*)(EA + (size_t)e0*64);
    if (tid < 256) *(float4*)&eas[tid>>4][(tid&15)*4] = ea4[tid];
  }
  if (tid < 16){ ssrc[tid] = EI[e0+tid]; sdst[tid] = EI[EE+e0+tid]; }
  __syncthreads();
  int cg = tid & 31, slot = tid >> 5;
  int c0 = cg*4, r0 = slot*2;
  float4 acc0 = make_float4(0,0,0,0), acc1 = make_float4(0,0,0,0);
#pragma unroll
  for (int k4=0;k4<16;++k4){
    float4 x0 = *(const float4*)&eas[r0][k4*4];
    float4 x1 = *(const float4*)&eas[r0+1][k4*4];
    const float* wb = &wel[(size_t)(k4*4)*128 + c0];
    float4 w0 = *(const float4*)(wb);
    float4 w1 = *(const float4*)(wb+128);
    float4 w2 = *(const float4*)(wb+256);
    float4 w3 = *(const float4*)(wb+384);
    fma4(acc0, x0.x, w0); fma4(acc0, x0.y, w1); fma4(acc0, x0.z, w2); fma4(acc0, x0.w, w3);
    fma4(acc1, x1.x, w0); fma4(acc1, x1.y, w1); fma4(acc1, x1.z, w2); fma4(acc1, x1.w, w3);
  }
  float4 at = *(const float4*)(ATT + c0);
  float4 xl0 = *(const float4*)(XL + (size_t)ssrc[r0]*128 + c0);
  float4 xr0 = *(const float4*)(XR + (size_t)sdst[r0]*128 + c0);
  float4 xl1 = *(const float4*)(XL + (size_t)ssrc[r0+1]*128 + c0);
  float4 xr1 = *(const float4*)(XR + (size_t)sdst[r0+1]*128 + c0);
  float4 s0 = lk4(make_float4(acc0.x+xl0.x+xr0.x, acc0.y+xl0.y+xr0.y, acc0.z+xl0.z+xr0.z, acc0.w+xl0.w+xr0.w));
  float4 s1 = lk4(make_float4(acc1.x+xl1.x+xr1.x, acc1.y+xl1.y+xr1.y, acc1.z+xl1.z+xr1.z, acc1.w+xl1.w+xr1.w));
  float pa0 = s0.x*at.x + s0.y*at.y + s0.z*at.z + s0.w*at.w;
  float pa1 = s1.x*at.x + s1.y*at.y + s1.z*at.z + s1.w*at.w;
  pa0 += __shfl_xor(pa0,1); pa0 += __shfl_xor(pa0,2); pa0 += __shfl_xor(pa0,4);
  pa1 += __shfl_xor(pa1,1); pa1 += __shfl_xor(pa1,2); pa1 += __shfl_xor(pa1,4);
  if ((tid & 7) == 0){
    int h = cg >> 3;
    ALPHA[(size_t)(e0+r0)*4 + h]   = pa0;
    ALPHA[(size_t)(e0+r0+1)*4 + h] = pa1;
  }
}

// ---------------- alpha layer 2: H=2, D=32, HD=64; 32 edges/block ----------------
__global__ __launch_bounds__(256) void k_alpha2(const float* __restrict__ XL, const float* __restrict__ XR,
    const float* __restrict__ EA, const float* __restrict__ WE, const float* __restrict__ ATT,
    const int* __restrict__ EI, float* __restrict__ ALPHA){
  __shared__ float wel[64*64];
  __shared__ float eas[32][64];
  __shared__ int ssrc[32], sdst[32];
  int tid = threadIdx.x;
  int e0 = blockIdx.x*32;
  for (int i=tid; i<64*64/4; i+=256) ((float4*)wel)[i] = ((const float4*)WE)[i];
  {
    const float4* ea4 = (const float4*)(EA + (size_t)e0*64);
    for (int i=tid; i<32*16; i+=256) *(float4*)&eas[i>>4][(i&15)*4] = ea4[i];
  }
  if (tid < 32){ ssrc[tid] = EI[e0+tid]; sdst[tid] = EI[EE+e0+tid]; }
  __syncthreads();
  int cg = tid & 15, slot = tid >> 4;
  int c0 = cg*4, r0 = slot*2;
  float4 acc0 = make_float4(0,0,0,0), acc1 = make_float4(0,0,0,0);
#pragma unroll
  for (int k4=0;k4<16;++k4){
    float4 x0 = *(const float4*)&eas[r0][k4*4];
    float4 x1 = *(const float4*)&eas[r0+1][k4*4];
    const float* wb = &wel[(size_t)(k4*4)*64 + c0];
    float4 w0 = *(const float4*)(wb);
    float4 w1 = *(const float4*)(wb+64);
    float4 w2 = *(const float4*)(wb+128);
    float4 w3 = *(const float4*)(wb+192);
    fma4(acc0, x0.x, w0); fma4(acc0, x0.y, w1); fma4(acc0, x0.z, w2); fma4(acc0, x0.w, w3);
    fma4(acc1, x1.x, w0); fma4(acc1, x1.y, w1); fma4(acc1, x1.z, w2); fma4(acc1, x1.w, w3);
  }
  float4 at = *(const float4*)(ATT + c0);
  float4 xl0 = *(const float4*)(XL + (size_t)ssrc[r0]*64 + c0);
  float4 xr0 = *(const float4*)(XR + (size_t)sdst[r0]*64 + c0);
  float4 xl1 = *(const float4*)(XL + (size_t)ssrc[r0+1]*64 + c0);
  float4 xr1 = *(const float4*)(XR + (size_t)sdst[r0+1]*64 + c0);
  float4 s0 = lk4(make_float4(acc0.x+xl0.x+xr0.x, acc0.y+xl0.y+xr0.y, acc0.z+xl0.z+xr0.z, acc0.w+xl0.w+xr0.w));
  float4 s1 = lk4(make_float4(acc1.x+xl1.x+xr1.x, acc1.y+xl1.y+xr1.y, acc1.z+xl1.z+xr1.z, acc1.w+xl1.w+xr1.w));
  float pa0 = s0.x*at.x + s0.y*at.y + s0.z*at.z + s0.w*at.w;
  float pa1 = s1.x*at.x + s1.y*at.y + s1.z*at.z + s1.w*at.w;
  pa0 += __shfl_xor(pa0,1); pa0 += __shfl_xor(pa0,2); pa0 += __shfl_xor(pa0,4);
  pa1 += __shfl_xor(pa1,1); pa1 += __shfl_xor(pa1,2); pa1 += __shfl_xor(pa1,4);
  if ((tid & 7) == 0){
    int h = cg >> 3;
    ALPHA[(size_t)(e0+r0)*2 + h]   = pa0;
    ALPHA[(size_t)(e0+r0+1)*2 + h] = pa1;
  }
}

// ---------------- gather layer 1: online softmax + LN + ELU fused ----------------
__global__ __launch_bounds__(256) void k_gather1(const float* __restrict__ XL, const float* __restrict__ ALPHA,
    const float* __restrict__ BIAS, const float* __restrict__ G_, const float* __restrict__ B_,
    const int* __restrict__ SRC, const int* __restrict__ OFF, const int* __restrict__ CSR,
    float* __restrict__ OUT){
  int t = threadIdx.x & 63;
  int n = blockIdx.x*4 + (threadIdx.x >> 6);
  int h = t >> 4;
  int beg = OFF[n], end = OFF[n+1];
  float m = -INFINITY, l = 0.f, a0 = 0.f, a1 = 0.f;
  for (int i=beg; i<end; ++i){
    int e = CSR[i];
    int s = SRC[e];
    float al = ALPHA[(size_t)e*4 + h];
    float2 xlv = *(const float2*)(XL + (size_t)s*128 + 2*t);
    if (al > m){
      float sc = __expf(m - al);   // m==-inf -> 0
      a0 = a0*sc + xlv.x; a1 = a1*sc + xlv.y; l = l*sc + 1.f; m = al;
    } else {
      float p = __expf(al - m);
      a0 += p*xlv.x; a1 += p*xlv.y; l += p;
    }
  }
  float inv = 1.f/(l + 1e-16f);
  float o0 = a0*inv + BIAS[2*t];
  float o1 = a1*inv + BIAS[2*t+1];
  // LN(128) + ELU
  float s = o0 + o1, q = o0*o0 + o1*o1;
#pragma unroll
  for (int o=1;o<64;o<<=1){ s += __shfl_xor(s,o); q += __shfl_xor(q,o); }
  float mean = s * (1.f/128.f);
  float var  = q * (1.f/128.f) - mean*mean;
  float r = rsqrtf(var + 1e-5f);
  float y0 = (o0-mean)*r*G_[2*t]   + B_[2*t];
  float y1 = (o1-mean)*r*G_[2*t+1] + B_[2*t+1];
  y0 = y0>0.f ? y0 : __expf(y0)-1.f;
  y1 = y1>0.f ? y1 : __expf(y1)-1.f;
  *(float2*)(OUT + (size_t)n*128 + 2*t) = make_float2(y0,y1);
}

// ---------------- gather layer 2: online softmax, raw out ----------------
__global__ __launch_bounds__(256) void k_gather2(const float* __restrict__ XL, const float* __restrict__ ALPHA,
    const float* __restrict__ BIAS, const int* __restrict__ SRC, const int* __restrict__ OFF,
    const int* __restrict__ CSR, float* __restrict__ OUT){
  int t = threadIdx.x & 63;
  int n = blockIdx.x*4 + (threadIdx.x >> 6);
  int h = t >> 5;
  int beg = OFF[n], end = OFF[n+1];
  float m = -INFINITY, l = 0.f, a0 = 0.f;
  for (int i=beg; i<end; ++i){
    int e = CSR[i];
    int s = SRC[e];
    float al = ALPHA[(size_t)e*2 + h];
    float xlv = XL[(size_t)s*64 + t];
    if (al > m){
      float sc = __expf(m - al);
      a0 = a0*sc + xlv; l = l*sc + 1.f; m = al;
    } else {
      float p = __expf(al - m);
      a0 += p*xlv; l += p;
    }
  }
  float inv = 1.f/(l + 1e-16f);
  OUT[(size_t)n*64 + t] = a0*inv + BIAS[t];
}

// ---------------- LN(64) + residual GEMV + ELU + gate MLP fused ----------------
__global__ __launch_bounds__(256) void k_res_gate(const float* __restrict__ GO, const float* __restrict__ H0,
    const float* __restrict__ RPW, const float* __restrict__ RPB_, const float* __restrict__ G_,
    const float* __restrict__ B_, const float* __restrict__ GT1, const float* __restrict__ GTB1,
    const float* __restrict__ GT2, const float* __restrict__ GTB2,
    float* __restrict__ NE, float* __restrict__ GATE){
  __shared__ float rl[64*64];
  __shared__ float gl[64*64];
  int tid = threadIdx.x, t = tid & 63, wv = tid >> 6;
  for (int i=tid; i<64*64/4; i+=256){
    ((float4*)rl)[i] = ((const float4*)RPW)[i];
    ((float4*)gl)[i] = ((const float4*)GT1)[i];
  }
  __syncthreads();
  int n = blockIdx.x*4 + wv;
  float x = GO[(size_t)n*64 + t];
  float s = x, q = x*x;
#pragma unroll
  for (int o=1;o<64;o<<=1){ s += __shfl_xor(s,o); q += __shfl_xor(q,o); }
  float mean = s * (1.f/64.f);
  float var  = q * (1.f/64.f) - mean*mean;
  float r = rsqrtf(var + 1e-5f);
  float ln = (x-mean)*r*G_[t] + B_[t];
  float h0v = H0[(size_t)n*64 + t];
  float acc = 0.f;
#pragma unroll 8
  for (int k=0;k<64;++k) acc += __shfl(h0v,k) * rl[k*64+t];
  float y = ln + acc + RPB_[t];
  y = y>0.f ? y : __expf(y)-1.f;
  NE[(size_t)n*64+t] = y;
  // gate: relu(y@GT1+b1) . GT2 + b2
  float mid = 0.f;
#pragma unroll 8
  for (int k=0;k<64;++k) mid += __shfl(y,k) * gl[k*64+t];
  float p = fmaxf(mid + GTB1[t], 0.f) * GT2[t];
#pragma unroll
  for (int o=1;o<64;o<<=1) p += __shfl_xor(p,o);
  if (t==0) GATE[n] = p + GTB2[0];
}

// ---------------- pooling ----------------
__global__ void k_pool_max(const float* __restrict__ GATE, const int* __restrict__ BATCH, u32* __restrict__ GMAX){
  int i = blockIdx.x*256 + threadIdx.x;
  if (i < NN) atomicMax(&GMAX[BATCH[i]], encf(GATE[i]));
}

__global__ __launch_bounds__(64) void k_pool_acc(const float* __restrict__ NE, const float* __restrict__ GATE,
    const int* __restrict__ BATCH, const u32* __restrict__ GMAX, float* __restrict__ GACC, float* __restrict__ GDEN){
  int t = threadIdx.x;
  int n0 = blockIdx.x*256;
  int n1 = n0+256; if (n1 > NN) n1 = NN;
  int curg = -1; float acc = 0.f, dl = 0.f, gm = 0.f;
  for (int n=n0; n<n1; ++n){
    int g = BATCH[n];
    if (g != curg){
      if (curg >= 0){ atomicAdd(&GACC[curg*64+t], acc); if (t==0) atomicAdd(&GDEN[curg], dl); }
      curg = g; acc = 0.f; dl = 0.f;
      float d = decf(GMAX[g]);
      gm = isfinite(d) ? d : 0.f;
    }
    float p = __expf(GATE[n] - gm);
    acc += p * NE[(size_t)n*64 + t];
    if (t==0) dl += p;
  }
  if (curg >= 0){ atomicAdd(&GACC[curg*64+t], acc); if (t==0) atomicAdd(&GDEN[curg], dl); }
}

__global__ __launch_bounds__(64) void k_scene(const float* __restrict__ GACC, const float* __restrict__ GDEN,
    const float* __restrict__ W1, const float* __restrict__ B1, const float* __restrict__ W2,
    const float* __restrict__ B2, float* __restrict__ Z){
  __shared__ float gv[GG][64];
  __shared__ float md[GG][64];
  int t = threadIdx.x;
  for (int g=0; g<GG; ++g) gv[g][t] = GACC[g*64+t] / (GDEN[g] + 1e-16f);
  __syncthreads();
  for (int g=0; g<GG; ++g){
    float m = 0.f;
    for (int k=0;k<64;++k) m += gv[g][k]*W1[k*64+t];
    md[g][t] = fmaxf(m + B1[t], 0.f);
  }
  __syncthreads();
  if (t < 32){
    for (int g=0; g<GG; ++g){
      float o = 0.f;
      for (int k=0;k<64;++k) o += md[g][k]*W2[k*32+t];
      Z[g*32+t] = o + B2[t];
    }
  }
}

// ---------------- launch ----------------
extern "C" void kernel_launch(void* const* d_in, const int* in_sizes, int n_in,
                              void* d_out, int out_size, void* d_ws, size_t ws_size,
                              hipStream_t stream){
  const float* x   = (const float*)d_in[0];
  const int* ei    = (const int*)d_in[1];
  const float* ea  = (const float*)d_in[2];
  const int* batch = (const int*)d_in[3];
  const float* ne_w1 = (const float*)d_in[4];  const float* ne_b1 = (const float*)d_in[5];
  const float* ne_w2 = (const float*)d_in[6];  const float* ne_b2 = (const float*)d_in[7];
  const float* ee_w1 = (const float*)d_in[8];  const float* ee_b1 = (const float*)d_in[9];
  const float* ee_w2 = (const float*)d_in[10]; const float* ee_b2 = (const float*)d_in[11];
  const float* g1_wl = (const float*)d_in[12]; const float* g1_bl = (const float*)d_in[13];
  const float* g1_wr = (const float*)d_in[14]; const float* g1_br = (const float*)d_in[15];
  const float* g1_we = (const float*)d_in[16];
  const float* g1_att= (const float*)d_in[17]; const float* g1_b  = (const float*)d_in[18];
  const float* n1_g  = (const float*)d_in[19]; const float* n1_b  = (const float*)d_in[20];
  const float* g2_wl = (const float*)d_in[21]; const float* g2_bl = (const float*)d_in[22];
  const float* g2_wr = (const float*)d_in[23]; const float* g2_br = (const float*)d_in[24];
  const float* g2_we = (const float*)d_in[25];
  const float* g2_att= (const float*)d_in[26]; const float* g2_b  = (const float*)d_in[27];
  const float* n2_g  = (const float*)d_in[28]; const float* n2_b  = (const float*)d_in[29];
  const float* rp_w  = (const float*)d_in[30]; const float* rp_b  = (const float*)d_in[31];
  const float* gt_w1 = (const float*)d_in[32]; const float* gt_b1 = (const float*)d_in[33];
  const float* gt_w2 = (const float*)d_in[34]; const float* gt_b2 = (const float*)d_in[35];
  const float* se_w1 = (const float*)d_in[36]; const float* se_b1 = (const float*)d_in[37];
  const float* se_w2 = (const float*)d_in[38]; const float* se_b2 = (const float*)d_in[39];

  char* ws = (char*)d_ws;
  size_t o = 0;
  auto alloc = [&](size_t bytes){ size_t r = o; o += (bytes + 255) & ~(size_t)255; return r; };
  float* h0    = (float*)(ws + alloc((size_t)NN*64*4));
  float* ta    = (float*)(ws + alloc((size_t)NN*128*4));   // mid / xl1 / xl2
  float* tb    = (float*)(ws + alloc((size_t)NN*128*4));   // xr1 / xr2
  float* tc    = (float*)(ws + alloc((size_t)NN*128*4));   // h1 / gat2 out
  float* alphab= (float*)(ws + alloc((size_t)EE*4*4));     // alpha1 [E,4] then alpha2 [E,2]
  float* gate  = (float*)(ws + alloc((size_t)NN*4));
  int*   cnt   = (int*)  (ws + alloc((size_t)NN*4));
  int*   off   = (int*)  (ws + alloc((size_t)(NN+1)*4));
  int*   csr   = (int*)  (ws + alloc((size_t)EE*4));
  char*  poolb = ws + alloc(4096);
  u32*   gmax  = (u32*)poolb;
  float* gden  = (float*)(poolb + 64);
  float* gacc  = (float*)(poolb + 128);
  if (o > ws_size) return;

  float* out_z  = (float*)d_out;
  float* out_ne = out_z + 256;
  float* out_er = out_ne + (size_t)NN*64;

  // CSR by dst
  hipMemsetAsync(cnt, 0, (size_t)NN*4, stream);
  hipMemsetAsync(poolb, 0, 4096, stream);
  k_count<<<(EE+255)/256, 256, 0, stream>>>(ei, cnt);
  k_scan<<<1, 1024, 0, stream>>>(cnt, off, cnt);
  k_scatter<<<(EE+255)/256, 256, 0, stream>>>(ei, cnt, csr);

  // node encoder: x -> mid(ta) -> h0
  k_lin<256,128,1><<<(NN+15)/16, 256, 0, stream>>>(x,  ne_w1, ne_b1, ta, NN);
  k_lin<128,64, 0><<<(NN+15)/16, 256, 0, stream>>>(ta, ne_w2, ne_b2, h0, NN);

  // GAT layer 1
  k_lin<64,128,0><<<(NN+15)/16, 256, 0, stream>>>(h0, g1_wl, g1_bl, ta, NN);
  k_lin<64,128,0><<<(NN+15)/16, 256, 0, stream>>>(h0, g1_wr, g1_br, tb, NN);
  k_alpha1<<<EE/16, 256, 0, stream>>>(ta, tb, ea, g1_we, g1_att, ei, alphab);
  k_gather1<<<NN/4, 256, 0, stream>>>(ta, alphab, g1_b, n1_g, n1_b, ei, off, csr, tc);

  // GAT layer 2
  k_lin<128,64,0><<<(NN+15)/16, 256, 0, stream>>>(tc, g2_wl, g2_bl, ta, NN);
  k_lin<128,64,0><<<(NN+15)/16, 256, 0, stream>>>(tc, g2_wr, g2_br, tb, NN);
  k_alpha2<<<EE/32, 256, 0, stream>>>(ta, tb, ea, g2_we, g2_att, ei, alphab);
  k_gather2<<<NN/4, 256, 0, stream>>>(ta, alphab, g2_b, ei, off, csr, tc);
  k_res_gate<<<NN/4, 256, 0, stream>>>(tc, h0, rp_w, rp_b, n2_g, n2_b,
                                       gt_w1, gt_b1, gt_w2, gt_b2, out_ne, gate);

  // edge representations (direct to d_out)
  k_edge_enc<<<EE/16, 256, 0, stream>>>(ea, ee_w1, ee_b1, ee_w2, ee_b2, out_er);

  // pooling + scene encoder
  k_pool_max<<<(NN+255)/256, 256, 0, stream>>>(gate, batch, gmax);
  k_pool_acc<<<(NN+255)/256, 64, 0, stream>>>(out_ne, gate, batch, gmax, gacc, gden);
  k_scene<<<1, 64, 0, stream>>>(gacc, gden, se_w1, se_b1, se_w2, se_b2, out_z);
}

// Round 4
// 1941.159 us; speedup vs baseline: 1.8187x; 1.3011x over previous
//
#include <hip/hip_runtime.h>
#include <cstdint>
#include <cstddef>

#define NN 50000
#define EE 800000
#define GG 8

typedef unsigned int u32;

__device__ __forceinline__ u32 encf(float f){
  u32 b = __float_as_uint(f);
  return (b & 0x80000000u) ? ~b : (b | 0x80000000u);
}
__device__ __forceinline__ float decf(u32 u){
  u32 b = (u & 0x80000000u) ? (u ^ 0x80000000u) : ~u;
  return __uint_as_float(b);
}
__device__ __forceinline__ void fma4(float4& a, float s, const float4& w){
  a.x += s*w.x; a.y += s*w.y; a.z += s*w.z; a.w += s*w.w;
}
__device__ __forceinline__ float4 lk4(float4 v){
  v.x = v.x>0.f ? v.x : 0.2f*v.x;
  v.y = v.y>0.f ? v.y : 0.2f*v.y;
  v.z = v.z>0.f ? v.z : 0.2f*v.z;
  v.w = v.w>0.f ? v.w : 0.2f*v.w;
  return v;
}

// ---------------- CSR build ----------------
__global__ void k_count(const int* __restrict__ ei, int* __restrict__ cnt){
  int e = blockIdx.x*256 + threadIdx.x;
  if (e < EE) atomicAdd(&cnt[ei[EE + e]], 1);
}

__global__ __launch_bounds__(1024) void k_scan(const int* __restrict__ CNT, int* __restrict__ OFF, int* __restrict__ CUR){
  __shared__ int buf[1024];
  __shared__ int carry_s;
  int tid = threadIdx.x;
  if (tid==0) carry_s = 0;
  __syncthreads();
  for (int base=0; base<NN; base+=1024){
    int v = (base+tid<NN) ? CNT[base+tid] : 0;
    buf[tid] = v; __syncthreads();
    for (int o=1;o<1024;o<<=1){
      int x = (tid>=o) ? buf[tid-o] : 0;
      __syncthreads();
      buf[tid] += x;
      __syncthreads();
    }
    int carry = carry_s;
    int excl = carry + buf[tid] - v;
    if (base+tid<NN){ OFF[base+tid]=excl; CUR[base+tid]=excl; }
    int tot = buf[1023];
    __syncthreads();
    if (tid==0) carry_s = carry + tot;
    __syncthreads();
  }
  if (tid==0) OFF[NN] = carry_s;
}

__global__ void k_scatter(const int* __restrict__ ei, int* __restrict__ cur, int* __restrict__ csr){
  int e = blockIdx.x*256 + threadIdx.x;
  if (e < EE){
    int d = ei[EE+e];
    int p = atomicAdd(&cur[d], 1);
    csr[p] = e;
  }
}

// ---------------- generic linear: Y = act(X @ W + b), k-vectorized ----------------
template<int CI, int CO, int ACT>
__global__ __launch_bounds__(256) void k_lin(const float* __restrict__ X, const float* __restrict__ W,
                                             const float* __restrict__ Bb, float* __restrict__ Y, int R){
  const int RPB = 16, SLOTS = 256/CO, J = RPB/SLOTS, NKC = CI/64;
  __shared__ float wl[64*CO];
  __shared__ float xs[RPB][68];
  int tid = threadIdx.x;
  int c = tid % CO, slot = tid / CO;
  int r0 = blockIdx.x * RPB;
  float acc[J];
#pragma unroll
  for (int j=0;j<J;++j) acc[j]=0.f;
  for (int kc=0; kc<NKC; ++kc){
    const float4* ws4 = (const float4*)(W + (size_t)kc*64*CO);
    float4* wl4 = (float4*)wl;
    for (int i=tid; i<64*CO/4; i+=256) wl4[i] = ws4[i];
    for (int i=tid; i<RPB*64; i+=256){
      int r = i>>6, k = i&63;
      float v = 0.f;
      if (r0 + r < R) v = X[(size_t)(r0+r)*CI + kc*64 + k];
      xs[r][k] = v;
    }
    __syncthreads();
#pragma unroll
    for (int k4=0;k4<16;++k4){
      float w0 = wl[(4*k4+0)*CO+c], w1 = wl[(4*k4+1)*CO+c];
      float w2 = wl[(4*k4+2)*CO+c], w3 = wl[(4*k4+3)*CO+c];
#pragma unroll
      for (int j=0;j<J;++j){
        float4 xv = *(const float4*)&xs[slot + j*SLOTS][k4*4];
        acc[j] += xv.x*w0 + xv.y*w1 + xv.z*w2 + xv.w*w3;
      }
    }
    __syncthreads();
  }
  float b = Bb ? Bb[c] : 0.f;
#pragma unroll
  for (int j=0;j<J;++j){
    int r = r0 + slot + j*SLOTS;
    if (r < R){
      float v = acc[j] + b;
      if (ACT==1) v = fmaxf(v, 0.f);
      Y[(size_t)r*CO + c] = v;
    }
  }
}

// ---------------- edge encoder: 64 edges/block, 4 rounds of 16 ----------------
__global__ __launch_bounds__(256) void k_edge_enc(const float* __restrict__ EA,
    const float* __restrict__ W1, const float* __restrict__ B1,
    const float* __restrict__ W2, const float* __restrict__ B2, float* __restrict__ OUT){
  __shared__ float w1l[64*64];
  __shared__ float w2l[64*64];
  __shared__ float xs[16][68];
  __shared__ float ms[16][68];
  int tid = threadIdx.x, c = tid & 63, slot = tid >> 6;
  for (int i=tid; i<64*64/4; i+=256){
    ((float4*)w1l)[i] = ((const float4*)W1)[i];
    ((float4*)w2l)[i] = ((const float4*)W2)[i];
  }
  float b1 = B1[c], b2 = B2[c];
  size_t ebase = (size_t)blockIdx.x * 64;
  for (int rnd=0; rnd<4; ++rnd){
    size_t base = (ebase + rnd*16) * 64;
    __syncthreads();   // covers w-load (rnd0) and xs/ms reuse (rnd>0)
    {
      const float4* ea4 = (const float4*)(EA + base);
      *(float4*)&xs[tid>>4][(tid&15)*4] = ea4[tid];
    }
    __syncthreads();
    float acc[4];
#pragma unroll
    for (int j=0;j<4;++j) acc[j]=0.f;
#pragma unroll
    for (int k4=0;k4<16;++k4){
      float w0 = w1l[(4*k4+0)*64+c], w1 = w1l[(4*k4+1)*64+c];
      float w2 = w1l[(4*k4+2)*64+c], w3 = w1l[(4*k4+3)*64+c];
#pragma unroll
      for (int j=0;j<4;++j){
        float4 xv = *(const float4*)&xs[j*4+slot][k4*4];
        acc[j] += xv.x*w0 + xv.y*w1 + xv.z*w2 + xv.w*w3;
      }
    }
#pragma unroll
    for (int j=0;j<4;++j) ms[j*4+slot][c] = fmaxf(acc[j] + b1, 0.f);
    __syncthreads();
#pragma unroll
    for (int j=0;j<4;++j) acc[j]=0.f;
#pragma unroll
    for (int k4=0;k4<16;++k4){
      float w0 = w2l[(4*k4+0)*64+c], w1 = w2l[(4*k4+1)*64+c];
      float w2 = w2l[(4*k4+2)*64+c], w3 = w2l[(4*k4+3)*64+c];
#pragma unroll
      for (int j=0;j<4;++j){
        float4 xv = *(const float4*)&ms[j*4+slot][k4*4];
        acc[j] += xv.x*w0 + xv.y*w1 + xv.z*w2 + xv.w*w3;
      }
    }
#pragma unroll
    for (int j=0;j<4;++j) OUT[base + (size_t)(j*4+slot)*64 + c] = acc[j] + b2;
  }
}

// ---------------- alpha layer 1: 64 edges/block (4 rounds of 16), H=4, HD=128 ----------------
__global__ __launch_bounds__(256) void k_alpha1(const float* __restrict__ XL, const float* __restrict__ XR,
    const float* __restrict__ EA, const float* __restrict__ WE, const float* __restrict__ ATT,
    const int* __restrict__ EI, float* __restrict__ ALPHA){
  __shared__ float wel[64*128];
  __shared__ float eas[16][64];
  __shared__ int ssrc[16], sdst[16];
  int tid = threadIdx.x;
  int ebase = blockIdx.x*64;
  for (int i=tid; i<64*128/4; i+=256) ((float4*)wel)[i] = ((const float4*)WE)[i];
  int cg = tid & 31, slot = tid >> 5;
  int c0 = cg*4, r0 = slot*2;
  float4 at = *(const float4*)(ATT + c0);
  for (int rnd=0; rnd<4; ++rnd){
    int e0 = ebase + rnd*16;
    __syncthreads();
    {
      const float4* ea4 = (const float4*)(EA + (size_t)e0*64);
      *(float4*)&eas[tid>>4][(tid&15)*4] = ea4[tid];
    }
    if (tid < 16){ ssrc[tid] = EI[e0+tid]; sdst[tid] = EI[EE+e0+tid]; }
    __syncthreads();
    float4 acc0 = make_float4(0,0,0,0), acc1 = make_float4(0,0,0,0);
#pragma unroll
    for (int k4=0;k4<16;++k4){
      float4 x0 = *(const float4*)&eas[r0][k4*4];
      float4 x1 = *(const float4*)&eas[r0+1][k4*4];
      const float* wb = &wel[(size_t)(k4*4)*128 + c0];
      float4 w0 = *(const float4*)(wb);
      float4 w1 = *(const float4*)(wb+128);
      float4 w2 = *(const float4*)(wb+256);
      float4 w3 = *(const float4*)(wb+384);
      fma4(acc0, x0.x, w0); fma4(acc0, x0.y, w1); fma4(acc0, x0.z, w2); fma4(acc0, x0.w, w3);
      fma4(acc1, x1.x, w0); fma4(acc1, x1.y, w1); fma4(acc1, x1.z, w2); fma4(acc1, x1.w, w3);
    }
    float4 xl0 = *(const float4*)(XL + (size_t)ssrc[r0]*128 + c0);
    float4 xr0 = *(const float4*)(XR + (size_t)sdst[r0]*128 + c0);
    float4 xl1 = *(const float4*)(XL + (size_t)ssrc[r0+1]*128 + c0);
    float4 xr1 = *(const float4*)(XR + (size_t)sdst[r0+1]*128 + c0);
    float4 s0 = lk4(make_float4(acc0.x+xl0.x+xr0.x, acc0.y+xl0.y+xr0.y, acc0.z+xl0.z+xr0.z, acc0.w+xl0.w+xr0.w));
    float4 s1 = lk4(make_float4(acc1.x+xl1.x+xr1.x, acc1.y+xl1.y+xr1.y, acc1.z+xl1.z+xr1.z, acc1.w+xl1.w+xr1.w));
    float pa0 = s0.x*at.x + s0.y*at.y + s0.z*at.z + s0.w*at.w;
    float pa1 = s1.x*at.x + s1.y*at.y + s1.z*at.z + s1.w*at.w;
    pa0 += __shfl_xor(pa0,1); pa0 += __shfl_xor(pa0,2); pa0 += __shfl_xor(pa0,4);
    pa1 += __shfl_xor(pa1,1); pa1 += __shfl_xor(pa1,2); pa1 += __shfl_xor(pa1,4);
    if ((tid & 7) == 0){
      int h = cg >> 3;
      ALPHA[(size_t)(e0+r0)*4 + h]   = pa0;
      ALPHA[(size_t)(e0+r0+1)*4 + h] = pa1;
    }
  }
}

// ---------------- alpha layer 2: 64 edges/block (2 rounds of 32), H=2, HD=64 ----------------
__global__ __launch_bounds__(256) void k_alpha2(const float* __restrict__ XL, const float* __restrict__ XR,
    const float* __restrict__ EA, const float* __restrict__ WE, const float* __restrict__ ATT,
    const int* __restrict__ EI, float* __restrict__ ALPHA){
  __shared__ float wel[64*64];
  __shared__ float eas[32][64];
  __shared__ int ssrc[32], sdst[32];
  int tid = threadIdx.x;
  int ebase = blockIdx.x*64;
  for (int i=tid; i<64*64/4; i+=256) ((float4*)wel)[i] = ((const float4*)WE)[i];
  int cg = tid & 15, slot = tid >> 4;
  int c0 = cg*4, r0 = slot*2;
  float4 at = *(const float4*)(ATT + c0);
  for (int rnd=0; rnd<2; ++rnd){
    int e0 = ebase + rnd*32;
    __syncthreads();
    {
      const float4* ea4 = (const float4*)(EA + (size_t)e0*64);
      for (int i=tid; i<32*16; i+=256) *(float4*)&eas[i>>4][(i&15)*4] = ea4[i];
    }
    if (tid < 32){ ssrc[tid] = EI[e0+tid]; sdst[tid] = EI[EE+e0+tid]; }
    __syncthreads();
    float4 acc0 = make_float4(0,0,0,0), acc1 = make_float4(0,0,0,0);
#pragma unroll
    for (int k4=0;k4<16;++k4){
      float4 x0 = *(const float4*)&eas[r0][k4*4];
      float4 x1 = *(const float4*)&eas[r0+1][k4*4];
      const float* wb = &wel[(size_t)(k4*4)*64 + c0];
      float4 w0 = *(const float4*)(wb);
      float4 w1 = *(const float4*)(wb+64);
      float4 w2 = *(const float4*)(wb+128);
      float4 w3 = *(const float4*)(wb+192);
      fma4(acc0, x0.x, w0); fma4(acc0, x0.y, w1); fma4(acc0, x0.z, w2); fma4(acc0, x0.w, w3);
      fma4(acc1, x1.x, w0); fma4(acc1, x1.y, w1); fma4(acc1, x1.z, w2); fma4(acc1, x1.w, w3);
    }
    float4 xl0 = *(const float4*)(XL + (size_t)ssrc[r0]*64 + c0);
    float4 xr0 = *(const float4*)(XR + (size_t)sdst[r0]*64 + c0);
    float4 xl1 = *(const float4*)(XL + (size_t)ssrc[r0+1]*64 + c0);
    float4 xr1 = *(const float4*)(XR + (size_t)sdst[r0+1]*64 + c0);
    float4 s0 = lk4(make_float4(acc0.x+xl0.x+xr0.x, acc0.y+xl0.y+xr0.y, acc0.z+xl0.z+xr0.z, acc0.w+xl0.w+xr0.w));
    float4 s1 = lk4(make_float4(acc1.x+xl1.x+xr1.x, acc1.y+xl1.y+xr1.y, acc1.z+xl1.z+xr1.z, acc1.w+xl1.w+xr1.w));
    float pa0 = s0.x*at.x + s0.y*at.y + s0.z*at.z + s0.w*at.w;
    float pa1 = s1.x*at.x + s1.y*at.y + s1.z*at.z + s1.w*at.w;
    pa0 += __shfl_xor(pa0,1); pa0 += __shfl_xor(pa0,2); pa0 += __shfl_xor(pa0,4);
    pa1 += __shfl_xor(pa1,1); pa1 += __shfl_xor(pa1,2); pa1 += __shfl_xor(pa1,4);
    if ((tid & 7) == 0){
      int h = cg >> 3;
      ALPHA[(size_t)(e0+r0)*2 + h]   = pa0;
      ALPHA[(size_t)(e0+r0+1)*2 + h] = pa1;
    }
  }
}

// ---------------- gather layer 1: online softmax + LN + ELU fused ----------------
__global__ __launch_bounds__(256) void k_gather1(const float* __restrict__ XL, const float* __restrict__ ALPHA,
    const float* __restrict__ BIAS, const float* __restrict__ G_, const float* __restrict__ B_,
    const int* __restrict__ SRC, const int* __restrict__ OFF, const int* __restrict__ CSR,
    float* __restrict__ OUT){
  int t = threadIdx.x & 63;
  int n = blockIdx.x*4 + (threadIdx.x >> 6);
  int h = t >> 4;
  int beg = OFF[n], end = OFF[n+1];
  float m = -INFINITY, l = 0.f, a0 = 0.f, a1 = 0.f;
  for (int i=beg; i<end; ++i){
    int e = CSR[i];
    int s = SRC[e];
    float al = ALPHA[(size_t)e*4 + h];
    float2 xlv = *(const float2*)(XL + (size_t)s*128 + 2*t);
    if (al > m){
      float sc = __expf(m - al);   // m==-inf -> 0
      a0 = a0*sc + xlv.x; a1 = a1*sc + xlv.y; l = l*sc + 1.f; m = al;
    } else {
      float p = __expf(al - m);
      a0 += p*xlv.x; a1 += p*xlv.y; l += p;
    }
  }
  float inv = 1.f/(l + 1e-16f);
  float o0 = a0*inv + BIAS[2*t];
  float o1 = a1*inv + BIAS[2*t+1];
  // LN(128) + ELU
  float s = o0 + o1, q = o0*o0 + o1*o1;
#pragma unroll
  for (int o=1;o<64;o<<=1){ s += __shfl_xor(s,o); q += __shfl_xor(q,o); }
  float mean = s * (1.f/128.f);
  float var  = q * (1.f/128.f) - mean*mean;
  float r = rsqrtf(var + 1e-5f);
  float y0 = (o0-mean)*r*G_[2*t]   + B_[2*t];
  float y1 = (o1-mean)*r*G_[2*t+1] + B_[2*t+1];
  y0 = y0>0.f ? y0 : __expf(y0)-1.f;
  y1 = y1>0.f ? y1 : __expf(y1)-1.f;
  *(float2*)(OUT + (size_t)n*128 + 2*t) = make_float2(y0,y1);
}

// ---------------- gather layer 2: online softmax, raw out ----------------
__global__ __launch_bounds__(256) void k_gather2(const float* __restrict__ XL, const float* __restrict__ ALPHA,
    const float* __restrict__ BIAS, const int* __restrict__ SRC, const int* __restrict__ OFF,
    const int* __restrict__ CSR, float* __restrict__ OUT){
  int t = threadIdx.x & 63;
  int n = blockIdx.x*4 + (threadIdx.x >> 6);
  int h = t >> 5;
  int beg = OFF[n], end = OFF[n+1];
  float m = -INFINITY, l = 0.f, a0 = 0.f;
  for (int i=beg; i<end; ++i){
    int e = CSR[i];
    int s = SRC[e];
    float al = ALPHA[(size_t)e*2 + h];
    float xlv = XL[(size_t)s*64 + t];
    if (al > m){
      float sc = __expf(m - al);
      a0 = a0*sc + xlv; l = l*sc + 1.f; m = al;
    } else {
      float p = __expf(al - m);
      a0 += p*xlv; l += p;
    }
  }
  float inv = 1.f/(l + 1e-16f);
  OUT[(size_t)n*64 + t] = a0*inv + BIAS[t];
}

// ---------------- LN(64) + residual GEMV + ELU + gate MLP fused (LDS GEMV) ----------------
__global__ __launch_bounds__(256) void k_res_gate(const float* __restrict__ GO, const float* __restrict__ H0,
    const float* __restrict__ RPW, const float* __restrict__ RPB_, const float* __restrict__ G_,
    const float* __restrict__ B_, const float* __restrict__ GT1, const float* __restrict__ GTB1,
    const float* __restrict__ GT2, const float* __restrict__ GTB2,
    float* __restrict__ NE, float* __restrict__ GATE){
  __shared__ float rlt[64*68];   // rlt[c][k] = RPW[k][c] (transposed)
  __shared__ float glt[64*68];
  __shared__ float xsw[4][64];
  __shared__ float ysw[4][64];
  int tid = threadIdx.x, t = tid & 63, wv = tid >> 6;
  for (int i=tid; i<64*64; i+=256){
    int k = i>>6, c = i&63;
    rlt[c*68+k] = RPW[i];
    glt[c*68+k] = GT1[i];
  }
  __syncthreads();
  int n = blockIdx.x*4 + wv;
  float x = GO[(size_t)n*64 + t];
  float s = x, q = x*x;
#pragma unroll
  for (int o=1;o<64;o<<=1){ s += __shfl_xor(s,o); q += __shfl_xor(q,o); }
  float mean = s * (1.f/64.f);
  float var  = q * (1.f/64.f) - mean*mean;
  float r = rsqrtf(var + 1e-5f);
  float ln = (x-mean)*r*G_[t] + B_[t];
  xsw[wv][t] = H0[(size_t)n*64 + t];     // same-wave write->read, lockstep safe
  float acc = 0.f;
#pragma unroll
  for (int k4=0;k4<16;++k4){
    float4 w  = *(const float4*)&rlt[t*68 + k4*4];
    float4 xv = *(const float4*)&xsw[wv][k4*4];
    acc += xv.x*w.x + xv.y*w.y + xv.z*w.z + xv.w*w.w;
  }
  float y = ln + acc + RPB_[t];
  y = y>0.f ? y : __expf(y)-1.f;
  NE[(size_t)n*64+t] = y;
  ysw[wv][t] = y;
  float mid = 0.f;
#pragma unroll
  for (int k4=0;k4<16;++k4){
    float4 w  = *(const float4*)&glt[t*68 + k4*4];
    float4 xv = *(const float4*)&ysw[wv][k4*4];
    mid += xv.x*w.x + xv.y*w.y + xv.z*w.z + xv.w*w.w;
  }
  float p = fmaxf(mid + GTB1[t], 0.f) * GT2[t];
#pragma unroll
  for (int o=1;o<64;o<<=1) p += __shfl_xor(p,o);
  if (t==0) GATE[n] = p + GTB2[0];
}

// ---------------- pooling ----------------
__global__ __launch_bounds__(256) void k_pool_max(const float* __restrict__ GATE, const int* __restrict__ BATCH, u32* __restrict__ GMAX){
  __shared__ u32 lmax[GG];
  int tid = threadIdx.x;
  if (tid < GG) lmax[tid] = 0u;
  __syncthreads();
  int base = blockIdx.x*1024;
#pragma unroll
  for (int j=0;j<4;++j){
    int i = base + j*256 + tid;
    if (i < NN) atomicMax(&lmax[BATCH[i]], encf(GATE[i]));
  }
  __syncthreads();
  if (tid < GG && lmax[tid] != 0u) atomicMax(&GMAX[tid], lmax[tid]);
}

__global__ __launch_bounds__(64) void k_pool_acc(const float* __restrict__ NE, const float* __restrict__ GATE,
    const int* __restrict__ BATCH, const u32* __restrict__ GMAX, float* __restrict__ GACC, float* __restrict__ GDEN){
  int t = threadIdx.x;
  int n0 = blockIdx.x*256;
  int n1 = n0+256; if (n1 > NN) n1 = NN;
  int curg = -1; float acc = 0.f, dl = 0.f, gm = 0.f;
  for (int n=n0; n<n1; ++n){
    int g = BATCH[n];
    if (g != curg){
      if (curg >= 0){ atomicAdd(&GACC[curg*64+t], acc); if (t==0) atomicAdd(&GDEN[curg], dl); }
      curg = g; acc = 0.f; dl = 0.f;
      float d = decf(GMAX[g]);
      gm = isfinite(d) ? d : 0.f;
    }
    float p = __expf(GATE[n] - gm);
    acc += p * NE[(size_t)n*64 + t];
    if (t==0) dl += p;
  }
  if (curg >= 0){ atomicAdd(&GACC[curg*64+t], acc); if (t==0) atomicAdd(&GDEN[curg], dl); }
}

__global__ __launch_bounds__(64) void k_scene(const float* __restrict__ GACC, const float* __restrict__ GDEN,
    const float* __restrict__ W1, const float* __restrict__ B1, const float* __restrict__ W2,
    const float* __restrict__ B2, float* __restrict__ Z){
  __shared__ float gv[GG][64];
  __shared__ float md[GG][64];
  int t = threadIdx.x;
  for (int g=0; g<GG; ++g) gv[g][t] = GACC[g*64+t] / (GDEN[g] + 1e-16f);
  __syncthreads();
  for (int g=0; g<GG; ++g){
    float m = 0.f;
    for (int k=0;k<64;++k) m += gv[g][k]*W1[k*64+t];
    md[g][t] = fmaxf(m + B1[t], 0.f);
  }
  __syncthreads();
  if (t < 32){
    for (int g=0; g<GG; ++g){
      float o = 0.f;
      for (int k=0;k<64;++k) o += md[g][k]*W2[k*32+t];
      Z[g*32+t] = o + B2[t];
    }
  }
}

// ---------------- launch ----------------
extern "C" void kernel_launch(void* const* d_in, const int* in_sizes, int n_in,
                              void* d_out, int out_size, void* d_ws, size_t ws_size,
                              hipStream_t stream){
  const float* x   = (const float*)d_in[0];
  const int* ei    = (const int*)d_in[1];
  const float* ea  = (const float*)d_in[2];
  const int* batch = (const int*)d_in[3];
  const float* ne_w1 = (const float*)d_in[4];  const float* ne_b1 = (const float*)d_in[5];
  const float* ne_w2 = (const float*)d_in[6];  const float* ne_b2 = (const float*)d_in[7];
  const float* ee_w1 = (const float*)d_in[8];  const float* ee_b1 = (const float*)d_in[9];
  const float* ee_w2 = (const float*)d_in[10]; const float* ee_b2 = (const float*)d_in[11];
  const float* g1_wl = (const float*)d_in[12]; const float* g1_bl = (const float*)d_in[13];
  const float* g1_wr = (const float*)d_in[14]; const float* g1_br = (const float*)d_in[15];
  const float* g1_we = (const float*)d_in[16];
  const float* g1_att= (const float*)d_in[17]; const float* g1_b  = (const float*)d_in[18];
  const float* n1_g  = (const float*)d_in[19]; const float* n1_b  = (const float*)d_in[20];
  const float* g2_wl = (const float*)d_in[21]; const float* g2_bl = (const float*)d_in[22];
  const float* g2_wr = (const float*)d_in[23]; const float* g2_br = (const float*)d_in[24];
  const float* g2_we = (const float*)d_in[25];
  const float* g2_att= (const float*)d_in[26]; const float* g2_b  = (const float*)d_in[27];
  const float* n2_g  = (const float*)d_in[28]; const float* n2_b  = (const float*)d_in[29];
  const float* rp_w  = (const float*)d_in[30]; const float* rp_b  = (const float*)d_in[31];
  const float* gt_w1 = (const float*)d_in[32]; const float* gt_b1 = (const float*)d_in[33];
  const float* gt_w2 = (const float*)d_in[34]; const float* gt_b2 = (const float*)d_in[35];
  const float* se_w1 = (const float*)d_in[36]; const float* se_b1 = (const float*)d_in[37];
  const float* se_w2 = (const float*)d_in[38]; const float* se_b2 = (const float*)d_in[39];

  char* ws = (char*)d_ws;
  size_t o = 0;
  auto alloc = [&](size_t bytes){ size_t r = o; o += (bytes + 255) & ~(size_t)255; return r; };
  float* h0    = (float*)(ws + alloc((size_t)NN*64*4));
  float* ta    = (float*)(ws + alloc((size_t)NN*128*4));   // mid / xl1 / xl2
  float* tb    = (float*)(ws + alloc((size_t)NN*128*4));   // xr1 / xr2
  float* tc    = (float*)(ws + alloc((size_t)NN*128*4));   // h1 / gat2 out
  float* alphab= (float*)(ws + alloc((size_t)EE*4*4));     // alpha1 [E,4] then alpha2 [E,2]
  float* gate  = (float*)(ws + alloc((size_t)NN*4));
  int*   cnt   = (int*)  (ws + alloc((size_t)NN*4));
  int*   off   = (int*)  (ws + alloc((size_t)(NN+1)*4));
  int*   csr   = (int*)  (ws + alloc((size_t)EE*4));
  char*  poolb = ws + alloc(4096);
  u32*   gmax  = (u32*)poolb;
  float* gden  = (float*)(poolb + 64);
  float* gacc  = (float*)(poolb + 128);
  if (o > ws_size) return;

  float* out_z  = (float*)d_out;
  float* out_ne = out_z + 256;
  float* out_er = out_ne + (size_t)NN*64;

  // CSR by dst
  hipMemsetAsync(cnt, 0, (size_t)NN*4, stream);
  hipMemsetAsync(poolb, 0, 4096, stream);
  k_count<<<(EE+255)/256, 256, 0, stream>>>(ei, cnt);
  k_scan<<<1, 1024, 0, stream>>>(cnt, off, cnt);
  k_scatter<<<(EE+255)/256, 256, 0, stream>>>(ei, cnt, csr);

  // node encoder: x -> mid(ta) -> h0
  k_lin<256,128,1><<<(NN+15)/16, 256, 0, stream>>>(x,  ne_w1, ne_b1, ta, NN);
  k_lin<128,64, 0><<<(NN+15)/16, 256, 0, stream>>>(ta, ne_w2, ne_b2, h0, NN);

  // GAT layer 1
  k_lin<64,128,0><<<(NN+15)/16, 256, 0, stream>>>(h0, g1_wl, g1_bl, ta, NN);
  k_lin<64,128,0><<<(NN+15)/16, 256, 0, stream>>>(h0, g1_wr, g1_br, tb, NN);
  k_alpha1<<<EE/64, 256, 0, stream>>>(ta, tb, ea, g1_we, g1_att, ei, alphab);
  k_gather1<<<NN/4, 256, 0, stream>>>(ta, alphab, g1_b, n1_g, n1_b, ei, off, csr, tc);

  // GAT layer 2
  k_lin<128,64,0><<<(NN+15)/16, 256, 0, stream>>>(tc, g2_wl, g2_bl, ta, NN);
  k_lin<128,64,0><<<(NN+15)/16, 256, 0, stream>>>(tc, g2_wr, g2_br, tb, NN);
  k_alpha2<<<EE/64, 256, 0, stream>>>(ta, tb, ea, g2_we, g2_att, ei, alphab);
  k_gather2<<<NN/4, 256, 0, stream>>>(ta, alphab, g2_b, ei, off, csr, tc);
  k_res_gate<<<NN/4, 256, 0, stream>>>(tc, h0, rp_w, rp_b, n2_g, n2_b,
                                       gt_w1, gt_b1, gt_w2, gt_b2, out_ne, gate);

  // edge representations (direct to d_out)
  k_edge_enc<<<EE/64, 256, 0, stream>>>(ea, ee_w1, ee_b1, ee_w2, ee_b2, out_er);

  // pooling + scene encoder
  k_pool_max<<<(NN+1023)/1024, 256, 0, stream>>>(gate, batch, gmax);
  k_pool_acc<<<(NN+255)/256, 64, 0, stream>>>(out_ne, gate, batch, gmax, gacc, gden);
  k_scene<<<1, 64, 0, stream>>>(gacc, gden, se_w1, se_b1, se_w2, se_b2, out_z);
}

// Round 5
// 1555.456 us; speedup vs baseline: 2.2697x; 1.2480x over previous
//
#include <hip/hip_runtime.h>
#include <cstdint>
#include <cstddef>

#define NN 50000
#define EE 800000
#define GG 8

typedef unsigned int u32;
typedef unsigned short u16;
typedef __attribute__((ext_vector_type(8))) short short8v;   // 8 bf16 = 4 VGPRs (A/B frag)
typedef __attribute__((ext_vector_type(4))) float f32x4;     // C/D frag

__device__ __forceinline__ u16 f2bf(float f){
  u32 b = __float_as_uint(f);
  u32 r = b + 0x7fffu + ((b>>16)&1u);
  return (u16)(r>>16);
}
__device__ __forceinline__ u32 encf(float f){
  u32 b = __float_as_uint(f);
  return (b & 0x80000000u) ? ~b : (b | 0x80000000u);
}
__device__ __forceinline__ float decf(u32 u){
  u32 b = (u & 0x80000000u) ? (u ^ 0x80000000u) : ~u;
  return __uint_as_float(b);
}

// ---------------- CSR build ----------------
__global__ void k_count(const int* __restrict__ ei, int* __restrict__ cnt){
  int e = blockIdx.x*256 + threadIdx.x;
  if (e < EE) atomicAdd(&cnt[ei[EE + e]], 1);
}

__global__ __launch_bounds__(1024) void k_scan(const int* __restrict__ CNT, int* __restrict__ OFF, int* __restrict__ CUR){
  __shared__ int buf[1024];
  __shared__ int carry_s;
  int tid = threadIdx.x;
  if (tid==0) carry_s = 0;
  __syncthreads();
  for (int base=0; base<NN; base+=1024){
    int v = (base+tid<NN) ? CNT[base+tid] : 0;
    buf[tid] = v; __syncthreads();
    for (int o=1;o<1024;o<<=1){
      int x = (tid>=o) ? buf[tid-o] : 0;
      __syncthreads();
      buf[tid] += x;
      __syncthreads();
    }
    int carry = carry_s;
    int excl = carry + buf[tid] - v;
    if (base+tid<NN){ OFF[base+tid]=excl; CUR[base+tid]=excl; }
    int tot = buf[1023];
    __syncthreads();
    if (tid==0) carry_s = carry + tot;
    __syncthreads();
  }
  if (tid==0) OFF[NN] = carry_s;
}

__global__ void k_scatter(const int* __restrict__ ei, int* __restrict__ cur, int* __restrict__ csr){
  int e = blockIdx.x*256 + threadIdx.x;
  if (e < EE){
    int d = ei[EE+e];
    int p = atomicAdd(&cur[d], 1);
    csr[p] = e;
  }
}

// ---------------- weight prep: bf16 transposed [n][k] layouts ----------------
// TW: [0,4096) ee1t[64][64]; [4096,8192) ee2t[64][64]; [8192,16384) we1t[128][64]; [16384,20480) we2t[64][64]
__global__ __launch_bounds__(256) void k_prep(const float* __restrict__ W_ee1,
    const float* __restrict__ W_ee2, const float* __restrict__ W_g1we,
    const float* __restrict__ W_g2we, u16* __restrict__ TW){
  int i = blockIdx.x*256 + threadIdx.x;
  if (i < 4096){
    int n=i>>6, k=i&63; TW[i] = f2bf(W_ee1[k*64+n]);
  } else if (i < 8192){
    int j=i-4096; int n=j>>6, k=j&63; TW[i] = f2bf(W_ee2[k*64+n]);
  } else if (i < 16384){
    int j=i-8192; int n=j>>6, k=j&63; TW[i] = f2bf(W_g1we[k*128+n]);
  } else if (i < 20480){
    int j=i-16384; int n=j>>6, k=j&63; TW[i] = f2bf(W_g2we[k*64+n]);
  }
}

// stage 64 edge rows (64 f32 each) -> LDS bf16 [64][80]
__device__ __forceinline__ void stage_ea(const float* __restrict__ EA, int e0, u16* ea_s, int tid){
  const float4* ea4 = (const float4*)(EA + (size_t)e0*64);
#pragma unroll
  for (int i=0;i<4;++i){
    int item = tid + i*256;
    int row = item>>4, c4 = item&15;
    float4 v = ea4[item];
    u32 p0 = (u32)f2bf(v.x) | ((u32)f2bf(v.y)<<16);
    u32 p1 = (u32)f2bf(v.z) | ((u32)f2bf(v.w)<<16);
    *(uint2*)&ea_s[row*80 + c4*4] = make_uint2(p0,p1);
  }
}

// ---------------- edge encoder: MFMA, 64 edges/block ----------------
__global__ __launch_bounds__(256) void k_edge_enc(const float* __restrict__ EA,
    const u16* __restrict__ WT1, const float* __restrict__ B1,
    const u16* __restrict__ WT2, const float* __restrict__ B2, float* __restrict__ OUT){
  __shared__ u16 ea_s[64*80];
  __shared__ u16 mid_s[64*80];
  int tid = threadIdx.x;
  int e0 = blockIdx.x*64;
  stage_ea(EA, e0, ea_s, tid);
  __syncthreads();
  int l = tid & 63, w = tid >> 6;
  int am = l & 15, kg = l >> 4;
  f32x4 acc[4];
#pragma unroll
  for (int nt=0;nt<4;++nt) acc[nt] = (f32x4){0.f,0.f,0.f,0.f};
#pragma unroll
  for (int ks=0;ks<2;++ks){
    short8v a = *(const short8v*)&ea_s[(w*16+am)*80 + ks*32 + kg*8];
#pragma unroll
    for (int nt=0;nt<4;++nt){
      short8v b = *(const short8v*)&WT1[(nt*16+am)*64 + ks*32 + kg*8];
      acc[nt] = __builtin_amdgcn_mfma_f32_16x16x32_bf16(a, b, acc[nt], 0, 0, 0);
    }
  }
#pragma unroll
  for (int nt=0;nt<4;++nt){
    int col = nt*16 + am;
    float bb = B1[col];
#pragma unroll
    for (int j=0;j<4;++j){
      float v = fmaxf(acc[nt][j] + bb, 0.f);
      mid_s[(w*16 + kg*4 + j)*80 + col] = f2bf(v);
    }
  }
  __syncthreads();
  f32x4 acc2[4];
#pragma unroll
  for (int nt=0;nt<4;++nt) acc2[nt] = (f32x4){0.f,0.f,0.f,0.f};
#pragma unroll
  for (int ks=0;ks<2;++ks){
    short8v a = *(const short8v*)&mid_s[(w*16+am)*80 + ks*32 + kg*8];
#pragma unroll
    for (int nt=0;nt<4;++nt){
      short8v b = *(const short8v*)&WT2[(nt*16+am)*64 + ks*32 + kg*8];
      acc2[nt] = __builtin_amdgcn_mfma_f32_16x16x32_bf16(a, b, acc2[nt], 0, 0, 0);
    }
  }
  float* outp = OUT + (size_t)(e0 + w*16)*64;
#pragma unroll
  for (int nt=0;nt<4;++nt){
    int col = nt*16 + am;
    float bb = B2[col];
#pragma unroll
    for (int j=0;j<4;++j){
      outp[(size_t)(kg*4+j)*64 + col] = acc2[nt][j] + bb;
    }
  }
}

// ---------------- alpha (GATv2 logits): MFMA ee-GEMM + gather epilogue ----------------
template<int HD>
__global__ __launch_bounds__(256) void k_alpha_mfma(const float* __restrict__ XL,
    const float* __restrict__ XR, const float* __restrict__ EA,
    const u16* __restrict__ WT, const float* __restrict__ ATT,
    const int* __restrict__ EI, float* __restrict__ ALPHA){
  const int NT = HD/16, H = HD/32;
  __shared__ u16 ea_s[64*80];
  __shared__ int ssrc[64], sdst[64];
  int tid = threadIdx.x;
  int e0 = blockIdx.x*64;
  stage_ea(EA, e0, ea_s, tid);
  if (tid < 64){ ssrc[tid] = EI[e0+tid]; sdst[tid] = EI[EE+e0+tid]; }
  __syncthreads();
  int l = tid & 63, w = tid >> 6;
  int am = l & 15, kg = l >> 4;
  f32x4 acc[NT];
#pragma unroll
  for (int nt=0;nt<NT;++nt) acc[nt] = (f32x4){0.f,0.f,0.f,0.f};
#pragma unroll
  for (int ks=0;ks<2;++ks){
    short8v a = *(const short8v*)&ea_s[(w*16+am)*80 + ks*32 + kg*8];
#pragma unroll
    for (int nt=0;nt<NT;++nt){
      short8v b = *(const short8v*)&WT[(nt*16+am)*64 + ks*32 + kg*8];
      acc[nt] = __builtin_amdgcn_mfma_f32_16x16x32_bf16(a, b, acc[nt], 0, 0, 0);
    }
  }
  float attv[NT];
#pragma unroll
  for (int nt=0;nt<NT;++nt) attv[nt] = ATT[nt*16 + am];
#pragma unroll
  for (int j=0;j<4;++j){
    int eloc = w*16 + kg*4 + j;
    const float* xlp = XL + (size_t)ssrc[eloc]*HD + am;
    const float* xrp = XR + (size_t)sdst[eloc]*HD + am;
#pragma unroll
    for (int h=0;h<H;++h){
      float sum = 0.f;
#pragma unroll
      for (int q=0;q<2;++q){
        int nt = h*2 + q;
        float s = acc[nt][j] + xlp[nt*16] + xrp[nt*16];
        s = s>0.f ? s : 0.2f*s;
        sum += s * attv[nt];
      }
      sum += __shfl_xor(sum,1); sum += __shfl_xor(sum,2);
      sum += __shfl_xor(sum,4); sum += __shfl_xor(sum,8);
      if (am==0) ALPHA[(size_t)(e0+eloc)*H + h] = sum;
    }
  }
}

// ---------------- generic linear: Y = act(X @ W + b), k-vectorized ----------------
template<int CI, int CO, int ACT>
__global__ __launch_bounds__(256) void k_lin(const float* __restrict__ X, const float* __restrict__ W,
                                             const float* __restrict__ Bb, float* __restrict__ Y, int R){
  const int RPB = 16, SLOTS = 256/CO, J = RPB/SLOTS, NKC = CI/64;
  __shared__ float wl[64*CO];
  __shared__ float xs[RPB][68];
  int tid = threadIdx.x;
  int c = tid % CO, slot = tid / CO;
  int r0 = blockIdx.x * RPB;
  float acc[J];
#pragma unroll
  for (int j=0;j<J;++j) acc[j]=0.f;
  for (int kc=0; kc<NKC; ++kc){
    const float4* ws4 = (const float4*)(W + (size_t)kc*64*CO);
    float4* wl4 = (float4*)wl;
    for (int i=tid; i<64*CO/4; i+=256) wl4[i] = ws4[i];
    for (int i=tid; i<RPB*64; i+=256){
      int r = i>>6, k = i&63;
      float v = 0.f;
      if (r0 + r < R) v = X[(size_t)(r0+r)*CI + kc*64 + k];
      xs[r][k] = v;
    }
    __syncthreads();
#pragma unroll
    for (int k4=0;k4<16;++k4){
      float w0 = wl[(4*k4+0)*CO+c], w1 = wl[(4*k4+1)*CO+c];
      float w2 = wl[(4*k4+2)*CO+c], w3 = wl[(4*k4+3)*CO+c];
#pragma unroll
      for (int j=0;j<J;++j){
        float4 xv = *(const float4*)&xs[slot + j*SLOTS][k4*4];
        acc[j] += xv.x*w0 + xv.y*w1 + xv.z*w2 + xv.w*w3;
      }
    }
    __syncthreads();
  }
  float b = Bb ? Bb[c] : 0.f;
#pragma unroll
  for (int j=0;j<J;++j){
    int r = r0 + slot + j*SLOTS;
    if (r < R){
      float v = acc[j] + b;
      if (ACT==1) v = fmaxf(v, 0.f);
      Y[(size_t)r*CO + c] = v;
    }
  }
}

// ---------------- gather layer 1: online softmax + LN + ELU fused ----------------
__global__ __launch_bounds__(256) void k_gather1(const float* __restrict__ XL, const float* __restrict__ ALPHA,
    const float* __restrict__ BIAS, const float* __restrict__ G_, const float* __restrict__ B_,
    const int* __restrict__ SRC, const int* __restrict__ OFF, const int* __restrict__ CSR,
    float* __restrict__ OUT){
  int t = threadIdx.x & 63;
  int n = blockIdx.x*4 + (threadIdx.x >> 6);
  int h = t >> 4;
  int beg = OFF[n], end = OFF[n+1];
  float m = -INFINITY, l = 0.f, a0 = 0.f, a1 = 0.f;
  for (int i=beg; i<end; ++i){
    int e = CSR[i];
    int s = SRC[e];
    float al = ALPHA[(size_t)e*4 + h];
    float2 xlv = *(const float2*)(XL + (size_t)s*128 + 2*t);
    if (al > m){
      float sc = __expf(m - al);   // m==-inf -> 0
      a0 = a0*sc + xlv.x; a1 = a1*sc + xlv.y; l = l*sc + 1.f; m = al;
    } else {
      float p = __expf(al - m);
      a0 += p*xlv.x; a1 += p*xlv.y; l += p;
    }
  }
  float inv = 1.f/(l + 1e-16f);
  float o0 = a0*inv + BIAS[2*t];
  float o1 = a1*inv + BIAS[2*t+1];
  // LN(128) + ELU
  float s = o0 + o1, q = o0*o0 + o1*o1;
#pragma unroll
  for (int o=1;o<64;o<<=1){ s += __shfl_xor(s,o); q += __shfl_xor(q,o); }
  float mean = s * (1.f/128.f);
  float var  = q * (1.f/128.f) - mean*mean;
  float r = rsqrtf(var + 1e-5f);
  float y0 = (o0-mean)*r*G_[2*t]   + B_[2*t];
  float y1 = (o1-mean)*r*G_[2*t+1] + B_[2*t+1];
  y0 = y0>0.f ? y0 : __expf(y0)-1.f;
  y1 = y1>0.f ? y1 : __expf(y1)-1.f;
  *(float2*)(OUT + (size_t)n*128 + 2*t) = make_float2(y0,y1);
}

// ---------------- gather layer 2: online softmax, raw out ----------------
__global__ __launch_bounds__(256) void k_gather2(const float* __restrict__ XL, const float* __restrict__ ALPHA,
    const float* __restrict__ BIAS, const int* __restrict__ SRC, const int* __restrict__ OFF,
    const int* __restrict__ CSR, float* __restrict__ OUT){
  int t = threadIdx.x & 63;
  int n = blockIdx.x*4 + (threadIdx.x >> 6);
  int h = t >> 5;
  int beg = OFF[n], end = OFF[n+1];
  float m = -INFINITY, l = 0.f, a0 = 0.f;
  for (int i=beg; i<end; ++i){
    int e = CSR[i];
    int s = SRC[e];
    float al = ALPHA[(size_t)e*2 + h];
    float xlv = XL[(size_t)s*64 + t];
    if (al > m){
      float sc = __expf(m - al);
      a0 = a0*sc + xlv; l = l*sc + 1.f; m = al;
    } else {
      float p = __expf(al - m);
      a0 += p*xlv; l += p;
    }
  }
  float inv = 1.f/(l + 1e-16f);
  OUT[(size_t)n*64 + t] = a0*inv + BIAS[t];
}

// ---------------- LN(64) + residual GEMV + ELU + gate MLP fused (LDS GEMV) ----------------
__global__ __launch_bounds__(256) void k_res_gate(const float* __restrict__ GO, const float* __restrict__ H0,
    const float* __restrict__ RPW, const float* __restrict__ RPB_, const float* __restrict__ G_,
    const float* __restrict__ B_, const float* __restrict__ GT1, const float* __restrict__ GTB1,
    const float* __restrict__ GT2, const float* __restrict__ GTB2,
    float* __restrict__ NE, float* __restrict__ GATE){
  __shared__ float rlt[64*68];   // rlt[c][k] = RPW[k][c] (transposed)
  __shared__ float glt[64*68];
  __shared__ float xsw[4][64];
  __shared__ float ysw[4][64];
  int tid = threadIdx.x, t = tid & 63, wv = tid >> 6;
  for (int i=tid; i<64*64; i+=256){
    int k = i>>6, c = i&63;
    rlt[c*68+k] = RPW[i];
    glt[c*68+k] = GT1[i];
  }
  __syncthreads();
  int n = blockIdx.x*4 + wv;
  float x = GO[(size_t)n*64 + t];
  float s = x, q = x*x;
#pragma unroll
  for (int o=1;o<64;o<<=1){ s += __shfl_xor(s,o); q += __shfl_xor(q,o); }
  float mean = s * (1.f/64.f);
  float var  = q * (1.f/64.f) - mean*mean;
  float r = rsqrtf(var + 1e-5f);
  float ln = (x-mean)*r*G_[t] + B_[t];
  xsw[wv][t] = H0[(size_t)n*64 + t];
  float acc = 0.f;
#pragma unroll
  for (int k4=0;k4<16;++k4){
    float4 w  = *(const float4*)&rlt[t*68 + k4*4];
    float4 xv = *(const float4*)&xsw[wv][k4*4];
    acc += xv.x*w.x + xv.y*w.y + xv.z*w.z + xv.w*w.w;
  }
  float y = ln + acc + RPB_[t];
  y = y>0.f ? y : __expf(y)-1.f;
  NE[(size_t)n*64+t] = y;
  ysw[wv][t] = y;
  float mid = 0.f;
#pragma unroll
  for (int k4=0;k4<16;++k4){
    float4 w  = *(const float4*)&glt[t*68 + k4*4];
    float4 xv = *(const float4*)&ysw[wv][k4*4];
    mid += xv.x*w.x + xv.y*w.y + xv.z*w.z + xv.w*w.w;
  }
  float p = fmaxf(mid + GTB1[t], 0.f) * GT2[t];
#pragma unroll
  for (int o=1;o<64;o<<=1) p += __shfl_xor(p,o);
  if (t==0) GATE[n] = p + GTB2[0];
}

// ---------------- pooling ----------------
__global__ __launch_bounds__(256) void k_pool_max(const float* __restrict__ GATE, const int* __restrict__ BATCH, u32* __restrict__ GMAX){
  __shared__ u32 lmax[GG];
  int tid = threadIdx.x;
  if (tid < GG) lmax[tid] = 0u;
  __syncthreads();
  int base = blockIdx.x*1024;
#pragma unroll
  for (int j=0;j<4;++j){
    int i = base + j*256 + tid;
    if (i < NN) atomicMax(&lmax[BATCH[i]], encf(GATE[i]));
  }
  __syncthreads();
  if (tid < GG && lmax[tid] != 0u) atomicMax(&GMAX[tid], lmax[tid]);
}

__global__ __launch_bounds__(64) void k_pool_acc(const float* __restrict__ NE, const float* __restrict__ GATE,
    const int* __restrict__ BATCH, const u32* __restrict__ GMAX, float* __restrict__ GACC, float* __restrict__ GDEN){
  int t = threadIdx.x;
  int n0 = blockIdx.x*256;
  int n1 = n0+256; if (n1 > NN) n1 = NN;
  int curg = -1; float acc = 0.f, dl = 0.f, gm = 0.f;
  for (int n=n0; n<n1; ++n){
    int g = BATCH[n];
    if (g != curg){
      if (curg >= 0){ atomicAdd(&GACC[curg*64+t], acc); if (t==0) atomicAdd(&GDEN[curg], dl); }
      curg = g; acc = 0.f; dl = 0.f;
      float d = decf(GMAX[g]);
      gm = isfinite(d) ? d : 0.f;
    }
    float p = __expf(GATE[n] - gm);
    acc += p * NE[(size_t)n*64 + t];
    if (t==0) dl += p;
  }
  if (curg >= 0){ atomicAdd(&GACC[curg*64+t], acc); if (t==0) atomicAdd(&GDEN[curg], dl); }
}

__global__ __launch_bounds__(64) void k_scene(const float* __restrict__ GACC, const float* __restrict__ GDEN,
    const float* __restrict__ W1, const float* __restrict__ B1, const float* __restrict__ W2,
    const float* __restrict__ B2, float* __restrict__ Z){
  __shared__ float gv[GG][64];
  __shared__ float md[GG][64];
  int t = threadIdx.x;
  for (int g=0; g<GG; ++g) gv[g][t] = GACC[g*64+t] / (GDEN[g] + 1e-16f);
  __syncthreads();
  for (int g=0; g<GG; ++g){
    float m = 0.f;
    for (int k=0;k<64;++k) m += gv[g][k]*W1[k*64+t];
    md[g][t] = fmaxf(m + B1[t], 0.f);
  }
  __syncthreads();
  if (t < 32){
    for (int g=0; g<GG; ++g){
      float o = 0.f;
      for (int k=0;k<64;++k) o += md[g][k]*W2[k*32+t];
      Z[g*32+t] = o + B2[t];
    }
  }
}

// ---------------- launch ----------------
extern "C" void kernel_launch(void* const* d_in, const int* in_sizes, int n_in,
                              void* d_out, int out_size, void* d_ws, size_t ws_size,
                              hipStream_t stream){
  const float* x   = (const float*)d_in[0];
  const int* ei    = (const int*)d_in[1];
  const float* ea  = (const float*)d_in[2];
  const int* batch = (const int*)d_in[3];
  const float* ne_w1 = (const float*)d_in[4];  const float* ne_b1 = (const float*)d_in[5];
  const float* ne_w2 = (const float*)d_in[6];  const float* ne_b2 = (const float*)d_in[7];
  const float* ee_w1 = (const float*)d_in[8];  const float* ee_b1 = (const float*)d_in[9];
  const float* ee_w2 = (const float*)d_in[10]; const float* ee_b2 = (const float*)d_in[11];
  const float* g1_wl = (const float*)d_in[12]; const float* g1_bl = (const float*)d_in[13];
  const float* g1_wr = (const float*)d_in[14]; const float* g1_br = (const float*)d_in[15];
  const float* g1_we = (const float*)d_in[16];
  const float* g1_att= (const float*)d_in[17]; const float* g1_b  = (const float*)d_in[18];
  const float* n1_g  = (const float*)d_in[19]; const float* n1_b  = (const float*)d_in[20];
  const float* g2_wl = (const float*)d_in[21]; const float* g2_bl = (const float*)d_in[22];
  const float* g2_wr = (const float*)d_in[23]; const float* g2_br = (const float*)d_in[24];
  const float* g2_we = (const float*)d_in[25];
  const float* g2_att= (const float*)d_in[26]; const float* g2_b  = (const float*)d_in[27];
  const float* n2_g  = (const float*)d_in[28]; const float* n2_b  = (const float*)d_in[29];
  const float* rp_w  = (const float*)d_in[30]; const float* rp_b  = (const float*)d_in[31];
  const float* gt_w1 = (const float*)d_in[32]; const float* gt_b1 = (const float*)d_in[33];
  const float* gt_w2 = (const float*)d_in[34]; const float* gt_b2 = (const float*)d_in[35];
  const float* se_w1 = (const float*)d_in[36]; const float* se_b1 = (const float*)d_in[37];
  const float* se_w2 = (const float*)d_in[38]; const float* se_b2 = (const float*)d_in[39];

  char* ws = (char*)d_ws;
  size_t o = 0;
  auto alloc = [&](size_t bytes){ size_t r = o; o += (bytes + 255) & ~(size_t)255; return r; };
  float* h0    = (float*)(ws + alloc((size_t)NN*64*4));
  float* ta    = (float*)(ws + alloc((size_t)NN*128*4));   // mid / xl1 / xl2
  float* tb    = (float*)(ws + alloc((size_t)NN*128*4));   // xr1 / xr2
  float* tc    = (float*)(ws + alloc((size_t)NN*128*4));   // h1 / gat2 out
  float* alphab= (float*)(ws + alloc((size_t)EE*4*4));     // alpha1 [E,4] then alpha2 [E,2]
  float* gate  = (float*)(ws + alloc((size_t)NN*4));
  int*   cnt   = (int*)  (ws + alloc((size_t)NN*4));
  int*   off   = (int*)  (ws + alloc((size_t)(NN+1)*4));
  int*   csr   = (int*)  (ws + alloc((size_t)EE*4));
  u16*   tw    = (u16*)  (ws + alloc(20480*2));            // bf16 transposed weights
  char*  poolb = ws + alloc(4096);
  u32*   gmax  = (u32*)poolb;
  float* gden  = (float*)(poolb + 64);
  float* gacc  = (float*)(poolb + 128);
  if (o > ws_size) return;

  float* out_z  = (float*)d_out;
  float* out_ne = out_z + 256;
  float* out_er = out_ne + (size_t)NN*64;

  // CSR by dst + weight prep
  hipMemsetAsync(cnt, 0, (size_t)NN*4, stream);
  hipMemsetAsync(poolb, 0, 4096, stream);
  k_count<<<(EE+255)/256, 256, 0, stream>>>(ei, cnt);
  k_scan<<<1, 1024, 0, stream>>>(cnt, off, cnt);
  k_scatter<<<(EE+255)/256, 256, 0, stream>>>(ei, cnt, csr);
  k_prep<<<80, 256, 0, stream>>>(ee_w1, ee_w2, g1_we, g2_we, tw);

  // node encoder: x -> mid(ta) -> h0
  k_lin<256,128,1><<<(NN+15)/16, 256, 0, stream>>>(x,  ne_w1, ne_b1, ta, NN);
  k_lin<128,64, 0><<<(NN+15)/16, 256, 0, stream>>>(ta, ne_w2, ne_b2, h0, NN);

  // GAT layer 1
  k_lin<64,128,0><<<(NN+15)/16, 256, 0, stream>>>(h0, g1_wl, g1_bl, ta, NN);
  k_lin<64,128,0><<<(NN+15)/16, 256, 0, stream>>>(h0, g1_wr, g1_br, tb, NN);
  k_alpha_mfma<128><<<EE/64, 256, 0, stream>>>(ta, tb, ea, tw + 8192, g1_att, ei, alphab);
  k_gather1<<<NN/4, 256, 0, stream>>>(ta, alphab, g1_b, n1_g, n1_b, ei, off, csr, tc);

  // GAT layer 2
  k_lin<128,64,0><<<(NN+15)/16, 256, 0, stream>>>(tc, g2_wl, g2_bl, ta, NN);
  k_lin<128,64,0><<<(NN+15)/16, 256, 0, stream>>>(tc, g2_wr, g2_br, tb, NN);
  k_alpha_mfma<64><<<EE/64, 256, 0, stream>>>(ta, tb, ea, tw + 16384, g2_att, ei, alphab);
  k_gather2<<<NN/4, 256, 0, stream>>>(ta, alphab, g2_b, ei, off, csr, tc);
  k_res_gate<<<NN/4, 256, 0, stream>>>(tc, h0, rp_w, rp_b, n2_g, n2_b,
                                       gt_w1, gt_b1, gt_w2, gt_b2, out_ne, gate);

  // edge representations (direct to d_out), MFMA
  k_edge_enc<<<EE/64, 256, 0, stream>>>(ea, tw, ee_b1, tw + 4096, ee_b2, out_er);

  // pooling + scene encoder
  k_pool_max<<<(NN+1023)/1024, 256, 0, stream>>>(gate, batch, gmax);
  k_pool_acc<<<(NN+255)/256, 64, 0, stream>>>(out_ne, gate, batch, gmax, gacc, gden);
  k_scene<<<1, 64, 0, stream>>>(gacc, gden, se_w1, se_b1, se_w2, se_b2, out_z);
}

// Round 6
// 1389.857 us; speedup vs baseline: 2.5401x; 1.1191x over previous
//
#include <hip/hip_runtime.h>
#include <cstdint>
#include <cstddef>

#define NN 50000
#define EE 800000
#define GG 8

typedef unsigned int u32;
typedef unsigned short u16;
typedef __attribute__((ext_vector_type(8))) short short8v;   // 8 bf16 = 4 VGPRs (A/B frag)
typedef __attribute__((ext_vector_type(4))) float f32x4;     // C/D frag

__device__ __forceinline__ u16 f2bf(float f){
  u32 b = __float_as_uint(f);
  u32 r = b + 0x7fffu + ((b>>16)&1u);
  return (u16)(r>>16);
}
__device__ __forceinline__ float bf2f(u16 v){ return __uint_as_float(((u32)v)<<16); }
__device__ __forceinline__ u32 encf(float f){
  u32 b = __float_as_uint(f);
  return (b & 0x80000000u) ? ~b : (b | 0x80000000u);
}
__device__ __forceinline__ float decf(u32 u){
  u32 b = (u & 0x80000000u) ? (u ^ 0x80000000u) : ~u;
  return __uint_as_float(b);
}

// ---------------- CSR build ----------------
__global__ void k_count(const int* __restrict__ ei, int* __restrict__ cnt){
  int e = blockIdx.x*256 + threadIdx.x;
  if (e < EE) atomicAdd(&cnt[ei[EE + e]], 1);
}

__global__ __launch_bounds__(1024) void k_scan(const int* __restrict__ CNT, int* __restrict__ OFF, int* __restrict__ CUR){
  __shared__ int buf[1024];
  __shared__ int carry_s;
  int tid = threadIdx.x;
  if (tid==0) carry_s = 0;
  __syncthreads();
  for (int base=0; base<NN; base+=1024){
    int v = (base+tid<NN) ? CNT[base+tid] : 0;
    buf[tid] = v; __syncthreads();
    for (int o=1;o<1024;o<<=1){
      int x = (tid>=o) ? buf[tid-o] : 0;
      __syncthreads();
      buf[tid] += x;
      __syncthreads();
    }
    int carry = carry_s;
    int excl = carry + buf[tid] - v;
    if (base+tid<NN){ OFF[base+tid]=excl; CUR[base+tid]=excl; }
    int tot = buf[1023];
    __syncthreads();
    if (tid==0) carry_s = carry + tot;
    __syncthreads();
  }
  if (tid==0) OFF[NN] = carry_s;
}

__global__ void k_scatter(const int* __restrict__ ei, int* __restrict__ cur,
                          int* __restrict__ csr, int* __restrict__ srcs, int* __restrict__ dsts){
  int e = blockIdx.x*256 + threadIdx.x;
  if (e < EE){
    int s = ei[e], d = ei[EE+e];
    int p = atomicAdd(&cur[d], 1);
    csr[p] = e; srcs[p] = s; dsts[p] = d;
  }
}

// ---------------- weight prep: bf16 transposed [n][k] layouts ----------------
// TW: [0,4096) ee1t[64][64]; [4096,8192) ee2t[64][64]; [8192,16384) we1t[128][64]; [16384,20480) we2t[64][64]
__global__ __launch_bounds__(256) void k_prep(const float* __restrict__ W_ee1,
    const float* __restrict__ W_ee2, const float* __restrict__ W_g1we,
    const float* __restrict__ W_g2we, u16* __restrict__ TW){
  int i = blockIdx.x*256 + threadIdx.x;
  if (i < 4096){
    int n=i>>6, k=i&63; TW[i] = f2bf(W_ee1[k*64+n]);
  } else if (i < 8192){
    int j=i-4096; int n=j>>6, k=j&63; TW[i] = f2bf(W_ee2[k*64+n]);
  } else if (i < 16384){
    int j=i-8192; int n=j>>6, k=j&63; TW[i] = f2bf(W_g1we[k*128+n]);
  } else if (i < 20480){
    int j=i-16384; int n=j>>6, k=j&63; TW[i] = f2bf(W_g2we[k*64+n]);
  }
}

// ---------------- mega1: edge encoder + alpha1, CSR order, 64 edges/block ----------------
__global__ __launch_bounds__(256) void k_mega1(const float* __restrict__ EA,
    const int* __restrict__ CSR, const int* __restrict__ SRCS, const int* __restrict__ DSTS,
    const u16* __restrict__ TW, const float* __restrict__ B1, const float* __restrict__ B2,
    const u16* __restrict__ XLb, const u16* __restrict__ XRb, const float* __restrict__ ATT,
    float* __restrict__ OUT_ER, float* __restrict__ ALPHA){
  __shared__ u16 ea_s[64*80];
  __shared__ u16 mid_s[64*80];
  __shared__ int ssrc[64], sdst[64], sedge[64];
  int tid = threadIdx.x;
  int i0 = blockIdx.x*64;
  if (tid < 64){ sedge[tid]=CSR[i0+tid]; ssrc[tid]=SRCS[i0+tid]; sdst[tid]=DSTS[i0+tid]; }
  __syncthreads();
#pragma unroll
  for (int i=0;i<4;++i){
    int item = tid + i*256;
    int row = item>>4, c4 = item&15;
    float4 v = ((const float4*)(EA + (size_t)sedge[row]*64))[c4];
    u32 p0 = (u32)f2bf(v.x) | ((u32)f2bf(v.y)<<16);
    u32 p1 = (u32)f2bf(v.z) | ((u32)f2bf(v.w)<<16);
    *(uint2*)&ea_s[row*80 + c4*4] = make_uint2(p0,p1);
  }
  __syncthreads();
  int l = tid & 63, w = tid >> 6;
  int am = l & 15, kg = l >> 4;
  short8v a0 = *(const short8v*)&ea_s[(w*16+am)*80 + 0  + kg*8];
  short8v a1 = *(const short8v*)&ea_s[(w*16+am)*80 + 32 + kg*8];
  // --- edge encoder: ea@W1 relu @W2 ---
  {
    f32x4 acc[4];
#pragma unroll
    for (int nt=0;nt<4;++nt) acc[nt] = (f32x4){0.f,0.f,0.f,0.f};
#pragma unroll
    for (int nt=0;nt<4;++nt){
      short8v b0 = *(const short8v*)&TW[(nt*16+am)*64 + 0  + kg*8];
      short8v b1 = *(const short8v*)&TW[(nt*16+am)*64 + 32 + kg*8];
      acc[nt] = __builtin_amdgcn_mfma_f32_16x16x32_bf16(a0, b0, acc[nt], 0, 0, 0);
      acc[nt] = __builtin_amdgcn_mfma_f32_16x16x32_bf16(a1, b1, acc[nt], 0, 0, 0);
    }
#pragma unroll
    for (int nt=0;nt<4;++nt){
      int col = nt*16 + am;
      float bb = B1[col];
#pragma unroll
      for (int j=0;j<4;++j){
        float v = fmaxf(acc[nt][j] + bb, 0.f);
        mid_s[(w*16 + kg*4 + j)*80 + col] = f2bf(v);
      }
    }
    __syncthreads();
    short8v m0 = *(const short8v*)&mid_s[(w*16+am)*80 + 0  + kg*8];
    short8v m1 = *(const short8v*)&mid_s[(w*16+am)*80 + 32 + kg*8];
    f32x4 acc2[4];
#pragma unroll
    for (int nt=0;nt<4;++nt) acc2[nt] = (f32x4){0.f,0.f,0.f,0.f};
#pragma unroll
    for (int nt=0;nt<4;++nt){
      short8v b0 = *(const short8v*)&TW[4096 + (nt*16+am)*64 + 0  + kg*8];
      short8v b1 = *(const short8v*)&TW[4096 + (nt*16+am)*64 + 32 + kg*8];
      acc2[nt] = __builtin_amdgcn_mfma_f32_16x16x32_bf16(m0, b0, acc2[nt], 0, 0, 0);
      acc2[nt] = __builtin_amdgcn_mfma_f32_16x16x32_bf16(m1, b1, acc2[nt], 0, 0, 0);
    }
#pragma unroll
    for (int nt=0;nt<4;++nt){
      int col = nt*16 + am;
      float bb = B2[col];
#pragma unroll
      for (int j=0;j<4;++j){
        int eglob = sedge[w*16 + kg*4 + j];
        OUT_ER[(size_t)eglob*64 + col] = acc2[nt][j] + bb;
      }
    }
  }
  // --- alpha1: ee = ea@WE1 (64->128), epilogue with bf16 node rows ---
  {
    f32x4 accw[8];
#pragma unroll
    for (int nt=0;nt<8;++nt) accw[nt] = (f32x4){0.f,0.f,0.f,0.f};
#pragma unroll
    for (int nt=0;nt<8;++nt){
      short8v b0 = *(const short8v*)&TW[8192 + (nt*16+am)*64 + 0  + kg*8];
      short8v b1 = *(const short8v*)&TW[8192 + (nt*16+am)*64 + 32 + kg*8];
      accw[nt] = __builtin_amdgcn_mfma_f32_16x16x32_bf16(a0, b0, accw[nt], 0, 0, 0);
      accw[nt] = __builtin_amdgcn_mfma_f32_16x16x32_bf16(a1, b1, accw[nt], 0, 0, 0);
    }
    float attv[8];
#pragma unroll
    for (int nt=0;nt<8;++nt) attv[nt] = ATT[nt*16 + am];
#pragma unroll
    for (int j=0;j<4;++j){
      int eloc = w*16 + kg*4 + j;
      const u16* xlp = XLb + (size_t)ssrc[eloc]*128 + am;
      const u16* xrp = XRb + (size_t)sdst[eloc]*128 + am;
#pragma unroll
      for (int h=0;h<4;++h){
        float sum = 0.f;
#pragma unroll
        for (int q=0;q<2;++q){
          int nt = h*2 + q;
          float s = accw[nt][j] + bf2f(xlp[nt*16]) + bf2f(xrp[nt*16]);
          s = s>0.f ? s : 0.2f*s;
          sum += s * attv[nt];
        }
        sum += __shfl_xor(sum,1); sum += __shfl_xor(sum,2);
        sum += __shfl_xor(sum,4); sum += __shfl_xor(sum,8);
        if (am==0) ALPHA[(size_t)(i0+eloc)*4 + h] = sum;
      }
    }
  }
}

// ---------------- alpha2: CSR order, MFMA ee2 + epilogue (H=2, HD=64) ----------------
__global__ __launch_bounds__(256) void k_alpha2m(const float* __restrict__ EA,
    const int* __restrict__ CSR, const int* __restrict__ SRCS, const int* __restrict__ DSTS,
    const u16* __restrict__ TW, const u16* __restrict__ XLb, const u16* __restrict__ XRb,
    const float* __restrict__ ATT, float* __restrict__ ALPHA){
  __shared__ u16 ea_s[64*80];
  __shared__ int ssrc[64], sdst[64], sedge[64];
  int tid = threadIdx.x;
  int i0 = blockIdx.x*64;
  if (tid < 64){ sedge[tid]=CSR[i0+tid]; ssrc[tid]=SRCS[i0+tid]; sdst[tid]=DSTS[i0+tid]; }
  __syncthreads();
#pragma unroll
  for (int i=0;i<4;++i){
    int item = tid + i*256;
    int row = item>>4, c4 = item&15;
    float4 v = ((const float4*)(EA + (size_t)sedge[row]*64))[c4];
    u32 p0 = (u32)f2bf(v.x) | ((u32)f2bf(v.y)<<16);
    u32 p1 = (u32)f2bf(v.z) | ((u32)f2bf(v.w)<<16);
    *(uint2*)&ea_s[row*80 + c4*4] = make_uint2(p0,p1);
  }
  __syncthreads();
  int l = tid & 63, w = tid >> 6;
  int am = l & 15, kg = l >> 4;
  short8v a0 = *(const short8v*)&ea_s[(w*16+am)*80 + 0  + kg*8];
  short8v a1 = *(const short8v*)&ea_s[(w*16+am)*80 + 32 + kg*8];
  f32x4 acc[4];
#pragma unroll
  for (int nt=0;nt<4;++nt) acc[nt] = (f32x4){0.f,0.f,0.f,0.f};
#pragma unroll
  for (int nt=0;nt<4;++nt){
    short8v b0 = *(const short8v*)&TW[16384 + (nt*16+am)*64 + 0  + kg*8];
    short8v b1 = *(const short8v*)&TW[16384 + (nt*16+am)*64 + 32 + kg*8];
    acc[nt] = __builtin_amdgcn_mfma_f32_16x16x32_bf16(a0, b0, acc[nt], 0, 0, 0);
    acc[nt] = __builtin_amdgcn_mfma_f32_16x16x32_bf16(a1, b1, acc[nt], 0, 0, 0);
  }
  float attv[4];
#pragma unroll
  for (int nt=0;nt<4;++nt) attv[nt] = ATT[nt*16 + am];
#pragma unroll
  for (int j=0;j<4;++j){
    int eloc = w*16 + kg*4 + j;
    const u16* xlp = XLb + (size_t)ssrc[eloc]*64 + am;
    const u16* xrp = XRb + (size_t)sdst[eloc]*64 + am;
#pragma unroll
    for (int h=0;h<2;++h){
      float sum = 0.f;
#pragma unroll
      for (int q=0;q<2;++q){
        int nt = h*2 + q;
        float s = acc[nt][j] + bf2f(xlp[nt*16]) + bf2f(xrp[nt*16]);
        s = s>0.f ? s : 0.2f*s;
        sum += s * attv[nt];
      }
      sum += __shfl_xor(sum,1); sum += __shfl_xor(sum,2);
      sum += __shfl_xor(sum,4); sum += __shfl_xor(sum,8);
      if (am==0) ALPHA[(size_t)(i0+eloc)*2 + h] = sum;
    }
  }
}

// ---------------- generic linear: Y = act(X @ W + b), f32 or bf16 out ----------------
template<int CI, int CO, int ACT, int BFO>
__global__ __launch_bounds__(256) void k_lin(const float* __restrict__ X, const float* __restrict__ W,
                                             const float* __restrict__ Bb, void* __restrict__ Yv, int R){
  const int RPB = 16, SLOTS = 256/CO, J = RPB/SLOTS, NKC = CI/64;
  __shared__ float wl[64*CO];
  __shared__ float xs[RPB][68];
  int tid = threadIdx.x;
  int c = tid % CO, slot = tid / CO;
  int r0 = blockIdx.x * RPB;
  float acc[J];
#pragma unroll
  for (int j=0;j<J;++j) acc[j]=0.f;
  for (int kc=0; kc<NKC; ++kc){
    const float4* ws4 = (const float4*)(W + (size_t)kc*64*CO);
    float4* wl4 = (float4*)wl;
    for (int i=tid; i<64*CO/4; i+=256) wl4[i] = ws4[i];
    for (int i=tid; i<RPB*64; i+=256){
      int r = i>>6, k = i&63;
      float v = 0.f;
      if (r0 + r < R) v = X[(size_t)(r0+r)*CI + kc*64 + k];
      xs[r][k] = v;
    }
    __syncthreads();
#pragma unroll
    for (int k4=0;k4<16;++k4){
      float w0 = wl[(4*k4+0)*CO+c], w1 = wl[(4*k4+1)*CO+c];
      float w2 = wl[(4*k4+2)*CO+c], w3 = wl[(4*k4+3)*CO+c];
#pragma unroll
      for (int j=0;j<J;++j){
        float4 xv = *(const float4*)&xs[slot + j*SLOTS][k4*4];
        acc[j] += xv.x*w0 + xv.y*w1 + xv.z*w2 + xv.w*w3;
      }
    }
    __syncthreads();
  }
  float b = Bb ? Bb[c] : 0.f;
#pragma unroll
  for (int j=0;j<J;++j){
    int r = r0 + slot + j*SLOTS;
    if (r < R){
      float v = acc[j] + b;
      if (ACT==1) v = fmaxf(v, 0.f);
      if (BFO) ((u16*)Yv)[(size_t)r*CO + c] = f2bf(v);
      else     ((float*)Yv)[(size_t)r*CO + c] = v;
    }
  }
}

// ---------------- gather layer 1: online softmax + LN + ELU fused ----------------
__global__ __launch_bounds__(256) void k_gather1(const u16* __restrict__ XLb, const float* __restrict__ ALPHA,
    const float* __restrict__ BIAS, const float* __restrict__ G_, const float* __restrict__ B_,
    const int* __restrict__ SRCS, const int* __restrict__ OFF, float* __restrict__ OUT){
  int t = threadIdx.x & 63;
  int n = blockIdx.x*4 + (threadIdx.x >> 6);
  int h = t >> 4;
  int beg = OFF[n], end = OFF[n+1];
  float m = -INFINITY, l = 0.f, a0 = 0.f, a1 = 0.f;
  for (int i=beg; i<end; ++i){
    int s = SRCS[i];
    float al = ALPHA[(size_t)i*4 + h];
    u32 v = *(const u32*)(XLb + (size_t)s*128 + 2*t);
    float x0 = __uint_as_float(v<<16);
    float x1 = __uint_as_float(v & 0xffff0000u);
    if (al > m){
      float sc = __expf(m - al);   // m==-inf -> 0
      a0 = a0*sc + x0; a1 = a1*sc + x1; l = l*sc + 1.f; m = al;
    } else {
      float p = __expf(al - m);
      a0 += p*x0; a1 += p*x1; l += p;
    }
  }
  float inv = 1.f/(l + 1e-16f);
  float o0 = a0*inv + BIAS[2*t];
  float o1 = a1*inv + BIAS[2*t+1];
  float s = o0 + o1, q = o0*o0 + o1*o1;
#pragma unroll
  for (int o=1;o<64;o<<=1){ s += __shfl_xor(s,o); q += __shfl_xor(q,o); }
  float mean = s * (1.f/128.f);
  float var  = q * (1.f/128.f) - mean*mean;
  float r = rsqrtf(var + 1e-5f);
  float y0 = (o0-mean)*r*G_[2*t]   + B_[2*t];
  float y1 = (o1-mean)*r*G_[2*t+1] + B_[2*t+1];
  y0 = y0>0.f ? y0 : __expf(y0)-1.f;
  y1 = y1>0.f ? y1 : __expf(y1)-1.f;
  *(float2*)(OUT + (size_t)n*128 + 2*t) = make_float2(y0,y1);
}

// ---------------- gather layer 2: online softmax, raw out ----------------
__global__ __launch_bounds__(256) void k_gather2(const u16* __restrict__ XLb, const float* __restrict__ ALPHA,
    const float* __restrict__ BIAS, const int* __restrict__ SRCS, const int* __restrict__ OFF,
    float* __restrict__ OUT){
  int t = threadIdx.x & 63;
  int n = blockIdx.x*4 + (threadIdx.x >> 6);
  int h = t >> 5;
  int beg = OFF[n], end = OFF[n+1];
  float m = -INFINITY, l = 0.f, a0 = 0.f;
  for (int i=beg; i<end; ++i){
    int s = SRCS[i];
    float al = ALPHA[(size_t)i*2 + h];
    float xlv = bf2f(XLb[(size_t)s*64 + t]);
    if (al > m){
      float sc = __expf(m - al);
      a0 = a0*sc + xlv; l = l*sc + 1.f; m = al;
    } else {
      float p = __expf(al - m);
      a0 += p*xlv; l += p;
    }
  }
  float inv = 1.f/(l + 1e-16f);
  OUT[(size_t)n*64 + t] = a0*inv + BIAS[t];
}

// ---------------- LN(64) + residual GEMV + ELU + gate MLP fused (LDS GEMV) ----------------
__global__ __launch_bounds__(256) void k_res_gate(const float* __restrict__ GO, const float* __restrict__ H0,
    const float* __restrict__ RPW, const float* __restrict__ RPB_, const float* __restrict__ G_,
    const float* __restrict__ B_, const float* __restrict__ GT1, const float* __restrict__ GTB1,
    const float* __restrict__ GT2, const float* __restrict__ GTB2,
    float* __restrict__ NE, float* __restrict__ GATE){
  __shared__ float rlt[64*68];
  __shared__ float glt[64*68];
  __shared__ float xsw[4][64];
  __shared__ float ysw[4][64];
  int tid = threadIdx.x, t = tid & 63, wv = tid >> 6;
  for (int i=tid; i<64*64; i+=256){
    int k = i>>6, c = i&63;
    rlt[c*68+k] = RPW[i];
    glt[c*68+k] = GT1[i];
  }
  __syncthreads();
  int n = blockIdx.x*4 + wv;
  float x = GO[(size_t)n*64 + t];
  float s = x, q = x*x;
#pragma unroll
  for (int o=1;o<64;o<<=1){ s += __shfl_xor(s,o); q += __shfl_xor(q,o); }
  float mean = s * (1.f/64.f);
  float var  = q * (1.f/64.f) - mean*mean;
  float r = rsqrtf(var + 1e-5f);
  float ln = (x-mean)*r*G_[t] + B_[t];
  xsw[wv][t] = H0[(size_t)n*64 + t];
  float acc = 0.f;
#pragma unroll
  for (int k4=0;k4<16;++k4){
    float4 w  = *(const float4*)&rlt[t*68 + k4*4];
    float4 xv = *(const float4*)&xsw[wv][k4*4];
    acc += xv.x*w.x + xv.y*w.y + xv.z*w.z + xv.w*w.w;
  }
  float y = ln + acc + RPB_[t];
  y = y>0.f ? y : __expf(y)-1.f;
  NE[(size_t)n*64+t] = y;
  ysw[wv][t] = y;
  float mid = 0.f;
#pragma unroll
  for (int k4=0;k4<16;++k4){
    float4 w  = *(const float4*)&glt[t*68 + k4*4];
    float4 xv = *(const float4*)&ysw[wv][k4*4];
    mid += xv.x*w.x + xv.y*w.y + xv.z*w.z + xv.w*w.w;
  }
  float p = fmaxf(mid + GTB1[t], 0.f) * GT2[t];
#pragma unroll
  for (int o=1;o<64;o<<=1) p += __shfl_xor(p,o);
  if (t==0) GATE[n] = p + GTB2[0];
}

// ---------------- pooling ----------------
__global__ __launch_bounds__(256) void k_pool_max(const float* __restrict__ GATE, const int* __restrict__ BATCH, u32* __restrict__ GMAX){
  __shared__ u32 lmax[GG];
  int tid = threadIdx.x;
  if (tid < GG) lmax[tid] = 0u;
  __syncthreads();
  int base = blockIdx.x*1024;
#pragma unroll
  for (int j=0;j<4;++j){
    int i = base + j*256 + tid;
    if (i < NN) atomicMax(&lmax[BATCH[i]], encf(GATE[i]));
  }
  __syncthreads();
  if (tid < GG && lmax[tid] != 0u) atomicMax(&GMAX[tid], lmax[tid]);
}

__global__ __launch_bounds__(64) void k_pool_acc(const float* __restrict__ NE, const float* __restrict__ GATE,
    const int* __restrict__ BATCH, const u32* __restrict__ GMAX, float* __restrict__ GACC, float* __restrict__ GDEN){
  int t = threadIdx.x;
  int n0 = blockIdx.x*256;
  int n1 = n0+256; if (n1 > NN) n1 = NN;
  int curg = -1; float acc = 0.f, dl = 0.f, gm = 0.f;
  for (int n=n0; n<n1; ++n){
    int g = BATCH[n];
    if (g != curg){
      if (curg >= 0){ atomicAdd(&GACC[curg*64+t], acc); if (t==0) atomicAdd(&GDEN[curg], dl); }
      curg = g; acc = 0.f; dl = 0.f;
      float d = decf(GMAX[g]);
      gm = isfinite(d) ? d : 0.f;
    }
    float p = __expf(GATE[n] - gm);
    acc += p * NE[(size_t)n*64 + t];
    if (t==0) dl += p;
  }
  if (curg >= 0){ atomicAdd(&GACC[curg*64+t], acc); if (t==0) atomicAdd(&GDEN[curg], dl); }
}

__global__ __launch_bounds__(64) void k_scene(const float* __restrict__ GACC, const float* __restrict__ GDEN,
    const float* __restrict__ W1, const float* __restrict__ B1, const float* __restrict__ W2,
    const float* __restrict__ B2, float* __restrict__ Z){
  __shared__ float gv[GG][64];
  __shared__ float md[GG][64];
  int t = threadIdx.x;
  for (int g=0; g<GG; ++g) gv[g][t] = GACC[g*64+t] / (GDEN[g] + 1e-16f);
  __syncthreads();
  for (int g=0; g<GG; ++g){
    float m = 0.f;
    for (int k=0;k<64;++k) m += gv[g][k]*W1[k*64+t];
    md[g][t] = fmaxf(m + B1[t], 0.f);
  }
  __syncthreads();
  if (t < 32){
    for (int g=0; g<GG; ++g){
      float o = 0.f;
      for (int k=0;k<64;++k) o += md[g][k]*W2[k*32+t];
      Z[g*32+t] = o + B2[t];
    }
  }
}

// ---------------- launch ----------------
extern "C" void kernel_launch(void* const* d_in, const int* in_sizes, int n_in,
                              void* d_out, int out_size, void* d_ws, size_t ws_size,
                              hipStream_t stream){
  const float* x   = (const float*)d_in[0];
  const int* ei    = (const int*)d_in[1];
  const float* ea  = (const float*)d_in[2];
  const int* batch = (const int*)d_in[3];
  const float* ne_w1 = (const float*)d_in[4];  const float* ne_b1 = (const float*)d_in[5];
  const float* ne_w2 = (const float*)d_in[6];  const float* ne_b2 = (const float*)d_in[7];
  const float* ee_w1 = (const float*)d_in[8];  const float* ee_b1 = (const float*)d_in[9];
  const float* ee_w2 = (const float*)d_in[10]; const float* ee_b2 = (const float*)d_in[11];
  const float* g1_wl = (const float*)d_in[12]; const float* g1_bl = (const float*)d_in[13];
  const float* g1_wr = (const float*)d_in[14]; const float* g1_br = (const float*)d_in[15];
  const float* g1_we = (const float*)d_in[16];
  const float* g1_att= (const float*)d_in[17]; const float* g1_b  = (const float*)d_in[18];
  const float* n1_g  = (const float*)d_in[19]; const float* n1_b  = (const float*)d_in[20];
  const float* g2_wl = (const float*)d_in[21]; const float* g2_bl = (const float*)d_in[22];
  const float* g2_wr = (const float*)d_in[23]; const float* g2_br = (const float*)d_in[24];
  const float* g2_we = (const float*)d_in[25];
  const float* g2_att= (const float*)d_in[26]; const float* g2_b  = (const float*)d_in[27];
  const float* n2_g  = (const float*)d_in[28]; const float* n2_b  = (const float*)d_in[29];
  const float* rp_w  = (const float*)d_in[30]; const float* rp_b  = (const float*)d_in[31];
  const float* gt_w1 = (const float*)d_in[32]; const float* gt_b1 = (const float*)d_in[33];
  const float* gt_w2 = (const float*)d_in[34]; const float* gt_b2 = (const float*)d_in[35];
  const float* se_w1 = (const float*)d_in[36]; const float* se_b1 = (const float*)d_in[37];
  const float* se_w2 = (const float*)d_in[38]; const float* se_b2 = (const float*)d_in[39];

  char* ws = (char*)d_ws;
  size_t o = 0;
  auto alloc = [&](size_t bytes){ size_t r = o; o += (bytes + 255) & ~(size_t)255; return r; };
  float* h0    = (float*)(ws + alloc((size_t)NN*64*4));
  float* ta    = (float*)(ws + alloc((size_t)NN*128*4));   // node-enc mid
  float* tc    = (float*)(ws + alloc((size_t)NN*128*4));   // h1, then gather2 out
  u16*   xl1b  = (u16*)  (ws + alloc((size_t)NN*128*2));
  u16*   xr1b  = (u16*)  (ws + alloc((size_t)NN*128*2));
  u16*   xl2b  = (u16*)  (ws + alloc((size_t)NN*64*2));
  u16*   xr2b  = (u16*)  (ws + alloc((size_t)NN*64*2));
  float* alphab= (float*)(ws + alloc((size_t)EE*4*4));     // slot-ordered [E,4] then [E,2]
  float* gate  = (float*)(ws + alloc((size_t)NN*4));
  int*   cnt   = (int*)  (ws + alloc((size_t)NN*4));
  int*   off   = (int*)  (ws + alloc((size_t)(NN+1)*4));
  int*   csr   = (int*)  (ws + alloc((size_t)EE*4));
  int*   srcs  = (int*)  (ws + alloc((size_t)EE*4));
  int*   dsts  = (int*)  (ws + alloc((size_t)EE*4));
  u16*   tw    = (u16*)  (ws + alloc(20480*2));
  char*  poolb = ws + alloc(4096);
  u32*   gmax  = (u32*)poolb;
  float* gden  = (float*)(poolb + 64);
  float* gacc  = (float*)(poolb + 128);
  if (o > ws_size) return;

  float* out_z  = (float*)d_out;
  float* out_ne = out_z + 256;
  float* out_er = out_ne + (size_t)NN*64;

  // CSR by dst + weight prep
  hipMemsetAsync(cnt, 0, (size_t)NN*4, stream);
  hipMemsetAsync(poolb, 0, 4096, stream);
  k_count<<<(EE+255)/256, 256, 0, stream>>>(ei, cnt);
  k_scan<<<1, 1024, 0, stream>>>(cnt, off, cnt);
  k_scatter<<<(EE+255)/256, 256, 0, stream>>>(ei, cnt, csr, srcs, dsts);
  k_prep<<<80, 256, 0, stream>>>(ee_w1, ee_w2, g1_we, g2_we, tw);

  // node encoder: x -> mid(ta) -> h0
  k_lin<256,128,1,0><<<(NN+15)/16, 256, 0, stream>>>(x,  ne_w1, ne_b1, ta, NN);
  k_lin<128,64, 0,0><<<(NN+15)/16, 256, 0, stream>>>(ta, ne_w2, ne_b2, h0, NN);

  // GAT layer 1 (+ fused edge encoder)
  k_lin<64,128,0,1><<<(NN+15)/16, 256, 0, stream>>>(h0, g1_wl, g1_bl, xl1b, NN);
  k_lin<64,128,0,1><<<(NN+15)/16, 256, 0, stream>>>(h0, g1_wr, g1_br, xr1b, NN);
  k_mega1<<<EE/64, 256, 0, stream>>>(ea, csr, srcs, dsts, tw, ee_b1, ee_b2,
                                     xl1b, xr1b, g1_att, out_er, alphab);
  k_gather1<<<NN/4, 256, 0, stream>>>(xl1b, alphab, g1_b, n1_g, n1_b, srcs, off, tc);

  // GAT layer 2
  k_lin<128,64,0,1><<<(NN+15)/16, 256, 0, stream>>>(tc, g2_wl, g2_bl, xl2b, NN);
  k_lin<128,64,0,1><<<(NN+15)/16, 256, 0, stream>>>(tc, g2_wr, g2_br, xr2b, NN);
  k_alpha2m<<<EE/64, 256, 0, stream>>>(ea, csr, srcs, dsts, tw, xl2b, xr2b, g2_att, alphab);
  k_gather2<<<NN/4, 256, 0, stream>>>(xl2b, alphab, g2_b, srcs, off, tc);
  k_res_gate<<<NN/4, 256, 0, stream>>>(tc, h0, rp_w, rp_b, n2_g, n2_b,
                                       gt_w1, gt_b1, gt_w2, gt_b2, out_ne, gate);

  // pooling + scene encoder
  k_pool_max<<<(NN+1023)/1024, 256, 0, stream>>>(gate, batch, gmax);
  k_pool_acc<<<(NN+255)/256, 64, 0, stream>>>(out_ne, gate, batch, gmax, gacc, gden);
  k_scene<<<1, 64, 0, stream>>>(gacc, gden, se_w1, se_b1, se_w2, se_b2, out_z);
}